// Round 9
// baseline (576.574 us; speedup 1.0000x reference)
//
#include <hip/hip_runtime.h>
#include <math.h>

#define N_NODES 50000
#define N_EDGES 800000
#define HIDDEN  128
#define EDIM    32
#define NEG     0.2f
#define NSLICE  8
#define SLICE_CH 16

typedef __attribute__((ext_vector_type(8))) short bshort8;
typedef __attribute__((ext_vector_type(4))) float f32x4;

__device__ __forceinline__ unsigned short f2bf(float f) {
    unsigned u = __builtin_bit_cast(unsigned, f);
    return (unsigned short)((u + 0x7FFFu + ((u >> 16) & 1u)) >> 16);
}
__device__ __forceinline__ float bf2f(unsigned short b) {
    unsigned u = ((unsigned)b) << 16;
    return __builtin_bit_cast(float, u);
}

// ---------------------------------------------------------------------------
// ce1 = We1 @ ae1, ce2 = We2 @ ae2 (each [32])
__global__ void prep_kernel(const float* __restrict__ We1, const float* __restrict__ ae1,
                            const float* __restrict__ We2, const float* __restrict__ ae2,
                            float* __restrict__ consts) {
    int t = threadIdx.x;
    if (t < 32) {
        float acc = 0.f;
        for (int k = 0; k < HIDDEN; k++) acc += We1[t * HIDDEN + k] * ae1[k];
        consts[t] = acc;
    } else if (t < 64) {
        int j = t - 32;
        float acc = 0.f;
        for (int k = 0; k < HIDDEN; k++) acc += We2[j * HIDDEN + k] * ae2[k];
        consts[32 + j] = acc;
    }
}

// ---------------------------------------------------------------------------
// Pack W (128x128 row-major, [k][col]) into MFMA B-fragment order, bf16 split.
__global__ void pack_w_kernel(const float* __restrict__ W,
                              unsigned short* __restrict__ whp,
                              unsigned short* __restrict__ wlp) {
    int idx = blockIdx.x * 256 + threadIdx.x;   // 16384 total
    int e  = idx & 7;
    int l  = (idx >> 3) & 63;
    int kc = (idx >> 9) & 3;
    int ct = (idx >> 11);
    int k   = kc * 32 + ((l >> 4) << 3) + e;
    int col = ct * 16 + (l & 15);
    float w = W[k * HIDDEN + col];
    unsigned short hb = f2bf(w);
    whp[idx] = hb;
    wlp[idx] = f2bf(w - bf2f(hb));
}

// ---------------------------------------------------------------------------
// CSR build
__global__ void hist_kernel(const int* __restrict__ dst, int* __restrict__ count) {
    int e = blockIdx.x * blockDim.x + threadIdx.x;
    if (e < N_EDGES) atomicAdd(&count[dst[e]], 1);
}

#define SCAN_BLOCKS ((N_NODES + 255) / 256)   // 196
__global__ void scan1_kernel(const int* __restrict__ count,
                             int* __restrict__ off_work, int* __restrict__ blocksum) {
    __shared__ int sh[256];
    int t = threadIdx.x;
    int idx = blockIdx.x * 256 + t;
    int v = (idx < N_NODES) ? count[idx] : 0;
    sh[t] = v;
    __syncthreads();
    for (int off = 1; off < 256; off <<= 1) {
        int u = (t >= off) ? sh[t - off] : 0;
        __syncthreads();
        sh[t] += u;
        __syncthreads();
    }
    if (idx < N_NODES) off_work[idx] = sh[t] - v;
    if (t == 255) blocksum[blockIdx.x] = sh[255];
}
__global__ void scan2_kernel(int* __restrict__ blocksum, int* __restrict__ blockoff) {
    __shared__ int sh[256];
    int t = threadIdx.x;
    int v = (t < SCAN_BLOCKS) ? blocksum[t] : 0;
    sh[t] = v;
    __syncthreads();
    for (int off = 1; off < 256; off <<= 1) {
        int u = (t >= off) ? sh[t - off] : 0;
        __syncthreads();
        sh[t] += u;
        __syncthreads();
    }
    if (t < SCAN_BLOCKS) blockoff[t] = sh[t] - v;
}
__global__ void scan3_kernel(int* __restrict__ off_work, const int* __restrict__ blockoff) {
    int idx = blockIdx.x * 256 + threadIdx.x;
    if (idx < N_NODES) off_work[idx] += blockoff[blockIdx.x];
}

__global__ void scatter_kernel(const int* __restrict__ src, const int* __restrict__ dst,
                               int* __restrict__ off_work,
                               int* __restrict__ src_p, int* __restrict__ ipos) {
    int e = blockIdx.x * blockDim.x + threadIdx.x;
    if (e >= N_EDGES) return;
    int pos = atomicAdd(&off_work[dst[e]], 1);
    src_p[pos] = src[e];
    ipos[e] = pos;
}

// ---------------------------------------------------------------------------
// ONE coalesced pass over ea computing BOTH layers' edge scalars.
__global__ void dotv_kernel(const float* __restrict__ ea, const float* __restrict__ consts,
                            const int* __restrict__ ipos,
                            float2* __restrict__ dotv_p, float* __restrict__ part) {
    __shared__ float cs[64];
    int t = threadIdx.x;
    if (t < 64) cs[t] = consts[t];
    __syncthreads();
    int e = blockIdx.x * blockDim.x + t;
    const float4* ep = (const float4*)(ea + (size_t)e * EDIM);
    float d1 = 0.f, d2 = 0.f;
#pragma unroll
    for (int i = 0; i < 8; i++) {
        float4 v = ep[i];
        d1 += v.x * cs[4 * i] + v.y * cs[4 * i + 1] + v.z * cs[4 * i + 2] + v.w * cs[4 * i + 3];
        d2 += v.x * cs[32 + 4 * i] + v.y * cs[32 + 4 * i + 1] + v.z * cs[32 + 4 * i + 2] + v.w * cs[32 + 4 * i + 3];
    }
    dotv_p[ipos[e]] = make_float2(d1, d2);
    float s1 = d1, s2 = d2;
    for (int off = 32; off > 0; off >>= 1) {
        s1 += __shfl_down(s1, off, 64);
        s2 += __shfl_down(s2, off, 64);
    }
    if ((t & 63) == 0) {
        int slot = (blockIdx.x & 63) * 16;
        atomicAdd(&part[slot], s1);
        atomicAdd(&part[slot + 1], s2);
    }
}

__global__ void reduce_sdv_kernel(const float* __restrict__ part, float* __restrict__ sdv) {
    int t = threadIdx.x;   // 64 threads
    float s1 = part[t * 16], s2 = part[t * 16 + 1];
    for (int off = 32; off > 0; off >>= 1) {
        s1 += __shfl_down(s1, off, 64);
        s2 += __shfl_down(s2, off, 64);
    }
    if (t == 0) { sdv[0] = s1; sdv[1] = s2; }
}

// ---------------------------------------------------------------------------
// MFMA gemm: h = x @ W via bf16 split; h stored BLOCKED [slice][N][16].
// ABLK=0: A row-major [N][128]; ABLK=1: A blocked [slice][N][16].
#define TILES_M (N_NODES / 16)                // 3125
#define GEMM_BLOCKS ((TILES_M + 3) / 4)       // 782
template<int ABLK>
__global__ void __launch_bounds__(256)
gemm_mfma_kernel(const float* __restrict__ x,
                 const unsigned short* __restrict__ wh,
                 const unsigned short* __restrict__ wl,
                 const float* __restrict__ a_s, const float* __restrict__ a_d,
                 float* __restrict__ h_t, float* __restrict__ alpha,
                 float* __restrict__ beta) {
    int tile = blockIdx.x * 4 + (threadIdx.x >> 6);
    if (tile >= TILES_M) return;
    int l    = threadIdx.x & 63;
    int row0 = tile * 16;
    int arow = l & 15;            // A row / D col
    int kg   = l >> 4;            // k-group / D row-group
    bshort8 ah[4], al[4];
#pragma unroll
    for (int kc = 0; kc < 4; kc++) {
        float4 f0, f1;
        if (ABLK == 0) {
            const float* xr = x + (size_t)(row0 + arow) * HIDDEN + (kg << 3);
            f0 = *(const float4*)(xr + kc * 32);
            f1 = *(const float4*)(xr + kc * 32 + 4);
        } else {
            int k0 = kc * 32 + (kg << 3);
            const float* xr = x + ((size_t)(k0 >> 4) * N_NODES + row0 + arow) * SLICE_CH + (k0 & 15);
            f0 = *(const float4*)xr;
            f1 = *(const float4*)(xr + 4);
        }
        float fv[8] = {f0.x, f0.y, f0.z, f0.w, f1.x, f1.y, f1.z, f1.w};
#pragma unroll
        for (int e = 0; e < 8; e++) {
            unsigned short hb = f2bf(fv[e]);
            ah[kc][e] = (short)hb;
            al[kc][e] = (short)f2bf(fv[e] - bf2f(hb));
        }
    }
    float pal[4] = {0.f, 0.f, 0.f, 0.f};
    float pbe[4] = {0.f, 0.f, 0.f, 0.f};
#pragma unroll
    for (int ct = 0; ct < 8; ct++) {
        f32x4 acc = {0.f, 0.f, 0.f, 0.f};
#pragma unroll
        for (int kc = 0; kc < 4; kc++) {
            int fo = (((ct * 4 + kc) * 64) + l) << 3;
            bshort8 bh = *(const bshort8*)(wh + fo);
            bshort8 bl = *(const bshort8*)(wl + fo);
            acc = __builtin_amdgcn_mfma_f32_16x16x32_bf16(ah[kc], bh, acc, 0, 0, 0);
            acc = __builtin_amdgcn_mfma_f32_16x16x32_bf16(al[kc], bh, acc, 0, 0, 0);
            acc = __builtin_amdgcn_mfma_f32_16x16x32_bf16(ah[kc], bl, acc, 0, 0, 0);
        }
        int col = ct * 16 + arow;
        float a_sc = a_s[col], a_dc = a_d[col];
#pragma unroll
        for (int j = 0; j < 4; j++) {
            // blocked store: slice=ct, channel-in-slice=arow
            h_t[((size_t)ct * N_NODES + row0 + kg * 4 + j) * SLICE_CH + arow] = acc[j];
            pal[j] += acc[j] * a_sc;
            pbe[j] += acc[j] * a_dc;
        }
    }
#pragma unroll
    for (int m = 1; m < 16; m <<= 1) {
#pragma unroll
        for (int j = 0; j < 4; j++) {
            pal[j] += __shfl_xor(pal[j], m, 64);
            pbe[j] += __shfl_xor(pbe[j], m, 64);
        }
    }
    if (arow == 0) {
#pragma unroll
        for (int j = 0; j < 4; j++) {
            alpha[row0 + kg * 4 + j] = pal[j];
            beta[row0 + kg * 4 + j]  = pbe[j];
        }
    }
}

// ---------------------------------------------------------------------------
// Per-node edge-weight pass (one wave per node): w_p[e]=exp(leaky(logit)),
// invd[i]=1/(wsum+exi+eps), selfw[i]=exi*invd.
template<int LAYER>
__global__ void __launch_bounds__(256)
w_pass_kernel(const int* __restrict__ off_work, const int* __restrict__ src_p,
              const float2* __restrict__ dotv_p,
              const float* __restrict__ alpha, const float* __restrict__ beta,
              const float* __restrict__ sdv,
              float* __restrict__ w_p, float* __restrict__ invd,
              float* __restrict__ selfw) {
    int t = threadIdx.x, l = t & 63;
    int i = blockIdx.x * 4 + (t >> 6);
    int start = (i == 0) ? 0 : off_work[i - 1];
    int end   = off_work[i];
    float beta_i = beta[i];
    float wl = 0.f;
    for (int e = start + l; e < end; e += 64) {
        float2 dv = dotv_p[e];
        float lg = alpha[src_p[e]] + beta_i + (LAYER == 0 ? dv.x : dv.y);
        lg = lg > 0.f ? lg : NEG * lg;
        float w = expf(lg);
        w_p[e] = w;
        wl += w;
    }
    for (int off = 32; off > 0; off >>= 1) wl += __shfl_down(wl, off, 64);
    if (l == 0) {
        float selfc = sdv[LAYER] * (1.f / (float)N_EDGES);
        float lg = alpha[i] + beta_i + selfc;
        lg = lg > 0.f ? lg : NEG * lg;
        float exi = expf(lg);
        float inv = 1.f / (wl + exi + 1e-16f);
        invd[i] = inv;
        selfw[i] = exi * inv;
    }
}

// ---------------------------------------------------------------------------
// Sliced gather-aggregate: slice = blockIdx&7 (one slice per XCD under
// round-robin dispatch -> 3.2 MB slice table is L2-resident). Wave per node:
// 4 edge-slots x 16 channels. Epilogue applies invd/selfw/bias.
// FINAL==0: write relu(v+b) blocked. FINAL==1: partial dot with Wlin,
// atomicAdd into outp[i] (zeroed by host).
template<int FINAL>
__global__ void __launch_bounds__(256)
agg_slice_kernel(const int* __restrict__ off_work, const int* __restrict__ src_p,
                 const float* __restrict__ w_p,
                 const float* __restrict__ invd, const float* __restrict__ selfw,
                 const float* __restrict__ h_t,
                 const float* __restrict__ b, const float* __restrict__ Wlin,
                 float* __restrict__ outp) {
    int t = threadIdx.x;
    int s = blockIdx.x & 7;
    int gid = blockIdx.x >> 3;
    int i = gid * 4 + (t >> 6);
    int l = t & 63, eo = l >> 4, c = l & 15;
    int start = (i == 0) ? 0 : off_work[i - 1];
    int end   = off_work[i];
    const float* hs = h_t + (size_t)s * N_NODES * SLICE_CH;
    float acc = 0.f;
    for (int e = start + eo; e < end; e += 4) {
        float w = w_p[e];
        int sj = src_p[e];
        acc += w * hs[(size_t)sj * SLICE_CH + c];
    }
    acc += __shfl_xor(acc, 16, 64);
    acc += __shfl_xor(acc, 32, 64);
    if (eo == 0) {
        float hv = hs[(size_t)i * SLICE_CH + c];
        float v = acc * invd[i] + selfw[i] * hv + b[s * SLICE_CH + c];
        if (FINAL == 0) {
            outp[((size_t)s * N_NODES + i) * SLICE_CH + c] = fmaxf(v, 0.f);
        } else {
            float contrib = v * Wlin[s * SLICE_CH + c];
            contrib += __shfl_xor(contrib, 1, 64);
            contrib += __shfl_xor(contrib, 2, 64);
            contrib += __shfl_xor(contrib, 4, 64);
            contrib += __shfl_xor(contrib, 8, 64);
            if (c == 0) atomicAdd(&outp[i], contrib);
        }
    }
}

// final: out[i] = relu(out[i] + bl)
__global__ void fin2_kernel(float* __restrict__ out, const float* __restrict__ bl) {
    int i = blockIdx.x * 256 + threadIdx.x;
    if (i < N_NODES) out[i] = fmaxf(out[i] + bl[0], 0.f);
}

// ---------------------------------------------------------------------------
extern "C" void kernel_launch(void* const* d_in, const int* in_sizes, int n_in,
                              void* d_out, int out_size, void* d_ws, size_t ws_size,
                              hipStream_t stream) {
    const float* x   = (const float*)d_in[0];
    const int*   src = (const int*)  d_in[1];
    const int*   dst = (const int*)  d_in[2];
    const float* ea  = (const float*)d_in[3];
    const float* W1  = (const float*)d_in[4];
    const float* We1 = (const float*)d_in[5];
    const float* as1 = (const float*)d_in[6];
    const float* ad1 = (const float*)d_in[7];
    const float* ae1 = (const float*)d_in[8];
    const float* b1  = (const float*)d_in[9];
    const float* W2  = (const float*)d_in[10];
    const float* We2 = (const float*)d_in[11];
    const float* as2 = (const float*)d_in[12];
    const float* ad2 = (const float*)d_in[13];
    const float* ae2 = (const float*)d_in[14];
    const float* b2  = (const float*)d_in[15];
    const float* Wl  = (const float*)d_in[16];
    const float* bl  = (const float*)d_in[17];
    float* out = (float*)d_out;

    float* ws      = (float*)d_ws;
    float* A       = ws;                           // [8][N][16] h (blocked)
    float* B       = A + (size_t)N_NODES * HIDDEN; // [8][N][16] out1 (blocked)
    unsigned short* whp1 = (unsigned short*)(B + (size_t)N_NODES * HIDDEN);
    unsigned short* wlp1 = whp1 + 16384;
    unsigned short* whp2 = wlp1 + 16384;
    unsigned short* wlp2 = whp2 + 16384;
    float* alpha   = (float*)(wlp2 + 16384);       // [N]
    float* beta    = alpha + N_NODES;              // [N]
    float2* dotv_p = (float2*)(beta + N_NODES);    // [E] (d1,d2) dst-sorted
    float* consts  = (float*)(dotv_p + N_EDGES);   // [64] ce1, ce2
    float* part    = consts + 64;                  // [64*16] padded partials
    float* sdv     = part + 64 * 16;               // [2]
    float* w_p     = sdv + 2;                      // [E] edge weights
    float* invd    = w_p + N_EDGES;                // [N]
    float* selfw   = invd + N_NODES;               // [N]
    int* count     = (int*)(selfw + N_NODES);      // [N]
    int* off_work  = count + N_NODES;              // [N]
    int* blocksum  = off_work + N_NODES;           // [SCAN_BLOCKS]
    int* blockoff  = blocksum + SCAN_BLOCKS;       // [SCAN_BLOCKS]
    int* src_p     = blockoff + SCAN_BLOCKS;       // [E] dst-sorted src ids
    int* ipos      = src_p + N_EDGES;              // [E] edge -> sorted slot

    const int EB = (N_EDGES + 255) / 256;

    // ---- prep: constants, W frag pack, CSR build, ea pass ----
    hipMemsetAsync(count, 0, N_NODES * sizeof(int), stream);
    hipMemsetAsync(part, 0, 64 * 16 * sizeof(float), stream);
    hipMemsetAsync(out, 0, N_NODES * sizeof(float), stream);   // final-dot acc
    prep_kernel<<<1, 64, 0, stream>>>(We1, ae1, We2, ae2, consts);
    pack_w_kernel<<<64, 256, 0, stream>>>(W1, whp1, wlp1);
    pack_w_kernel<<<64, 256, 0, stream>>>(W2, whp2, wlp2);
    hist_kernel<<<EB, 256, 0, stream>>>(dst, count);
    scan1_kernel<<<SCAN_BLOCKS, 256, 0, stream>>>(count, off_work, blocksum);
    scan2_kernel<<<1, 256, 0, stream>>>(blocksum, blockoff);
    scan3_kernel<<<SCAN_BLOCKS, 256, 0, stream>>>(off_work, blockoff);
    scatter_kernel<<<EB, 256, 0, stream>>>(src, dst, off_work, src_p, ipos);
    dotv_kernel<<<EB, 256, 0, stream>>>(ea, consts, ipos, dotv_p, part);
    reduce_sdv_kernel<<<1, 64, 0, stream>>>(part, sdv);

    // ---- conv1 ----
    gemm_mfma_kernel<0><<<GEMM_BLOCKS, 256, 0, stream>>>(x, whp1, wlp1, as1, ad1,
                                                         A, alpha, beta);
    w_pass_kernel<0><<<N_NODES / 4, 256, 0, stream>>>(off_work, src_p, dotv_p,
                                                      alpha, beta, sdv, w_p, invd, selfw);
    agg_slice_kernel<0><<<(N_NODES / 4) * 8, 256, 0, stream>>>(off_work, src_p, w_p,
                                                               invd, selfw, A, b1,
                                                               nullptr, B);

    // ---- conv2 (+ final linear) ----
    gemm_mfma_kernel<1><<<GEMM_BLOCKS, 256, 0, stream>>>(B, whp2, wlp2, as2, ad2,
                                                         A, alpha, beta);
    w_pass_kernel<1><<<N_NODES / 4, 256, 0, stream>>>(off_work, src_p, dotv_p,
                                                      alpha, beta, sdv, w_p, invd, selfw);
    agg_slice_kernel<1><<<(N_NODES / 4) * 8, 256, 0, stream>>>(off_work, src_p, w_p,
                                                               invd, selfw, A, b2,
                                                               Wl, out);
    fin2_kernel<<<(N_NODES + 255) / 256, 256, 0, stream>>>(out, bl);
}

// Round 10
// 305.084 us; speedup vs baseline: 1.8899x; 1.8899x over previous
//
#include <hip/hip_runtime.h>
#include <math.h>

#define N_NODES 50000
#define N_EDGES 800000
#define HIDDEN  128
#define EDIM    32
#define NEG     0.2f

typedef __attribute__((ext_vector_type(8))) short bshort8;
typedef __attribute__((ext_vector_type(4))) float f32x4;

__device__ __forceinline__ unsigned short f2bf(float f) {
    unsigned u = __builtin_bit_cast(unsigned, f);
    return (unsigned short)((u + 0x7FFFu + ((u >> 16) & 1u)) >> 16);
}
__device__ __forceinline__ float bf2f(unsigned short b) {
    unsigned u = ((unsigned)b) << 16;
    return __builtin_bit_cast(float, u);
}

// ---------------------------------------------------------------------------
// ce1 = We1 @ ae1, ce2 = We2 @ ae2 (each [32])
__global__ void prep_kernel(const float* __restrict__ We1, const float* __restrict__ ae1,
                            const float* __restrict__ We2, const float* __restrict__ ae2,
                            float* __restrict__ consts) {
    int t = threadIdx.x;
    if (t < 32) {
        float acc = 0.f;
        for (int k = 0; k < HIDDEN; k++) acc += We1[t * HIDDEN + k] * ae1[k];
        consts[t] = acc;
    } else if (t < 64) {
        int j = t - 32;
        float acc = 0.f;
        for (int k = 0; k < HIDDEN; k++) acc += We2[j * HIDDEN + k] * ae2[k];
        consts[32 + j] = acc;
    }
}

// ---------------------------------------------------------------------------
// Pack W (128x128 row-major, [k][col]) into MFMA B-fragment order, bf16 split.
__global__ void pack_w_kernel(const float* __restrict__ W,
                              unsigned short* __restrict__ whp,
                              unsigned short* __restrict__ wlp) {
    int idx = blockIdx.x * 256 + threadIdx.x;   // 16384 total
    int e  = idx & 7;
    int l  = (idx >> 3) & 63;
    int kc = (idx >> 9) & 3;
    int ct = (idx >> 11);
    int k   = kc * 32 + ((l >> 4) << 3) + e;
    int col = ct * 16 + (l & 15);
    float w = W[k * HIDDEN + col];
    unsigned short hb = f2bf(w);
    whp[idx] = hb;
    wlp[idx] = f2bf(w - bf2f(hb));
}

// ---------------------------------------------------------------------------
// CSR build
__global__ void hist_kernel(const int* __restrict__ dst, int* __restrict__ count) {
    int e = blockIdx.x * blockDim.x + threadIdx.x;
    if (e < N_EDGES) atomicAdd(&count[dst[e]], 1);
}

#define SCAN_BLOCKS ((N_NODES + 255) / 256)   // 196
__global__ void scan1_kernel(const int* __restrict__ count,
                             int* __restrict__ off_work, int* __restrict__ blocksum) {
    __shared__ int sh[256];
    int t = threadIdx.x;
    int idx = blockIdx.x * 256 + t;
    int v = (idx < N_NODES) ? count[idx] : 0;
    sh[t] = v;
    __syncthreads();
    for (int off = 1; off < 256; off <<= 1) {
        int u = (t >= off) ? sh[t - off] : 0;
        __syncthreads();
        sh[t] += u;
        __syncthreads();
    }
    if (idx < N_NODES) off_work[idx] = sh[t] - v;
    if (t == 255) blocksum[blockIdx.x] = sh[255];
}
__global__ void scan2_kernel(int* __restrict__ blocksum, int* __restrict__ blockoff) {
    __shared__ int sh[256];
    int t = threadIdx.x;
    int v = (t < SCAN_BLOCKS) ? blocksum[t] : 0;
    sh[t] = v;
    __syncthreads();
    for (int off = 1; off < 256; off <<= 1) {
        int u = (t >= off) ? sh[t - off] : 0;
        __syncthreads();
        sh[t] += u;
        __syncthreads();
    }
    if (t < SCAN_BLOCKS) blockoff[t] = sh[t] - v;
}
__global__ void scan3_kernel(int* __restrict__ off_work, const int* __restrict__ blockoff) {
    int idx = blockIdx.x * 256 + threadIdx.x;
    if (idx < N_NODES) off_work[idx] += blockoff[blockIdx.x];
}

__global__ void scatter_kernel(const int* __restrict__ src, const int* __restrict__ dst,
                               int* __restrict__ off_work,
                               int* __restrict__ src_p, int* __restrict__ ipos) {
    int e = blockIdx.x * blockDim.x + threadIdx.x;
    if (e >= N_EDGES) return;
    int pos = atomicAdd(&off_work[dst[e]], 1);
    src_p[pos] = src[e];
    ipos[e] = pos;
}

// ---------------------------------------------------------------------------
// ONE coalesced pass over ea computing BOTH layers' edge scalars.
__global__ void dotv_kernel(const float* __restrict__ ea, const float* __restrict__ consts,
                            const int* __restrict__ ipos,
                            float2* __restrict__ dotv_p, float* __restrict__ part) {
    __shared__ float cs[64];
    int t = threadIdx.x;
    if (t < 64) cs[t] = consts[t];
    __syncthreads();
    int e = blockIdx.x * blockDim.x + t;
    const float4* ep = (const float4*)(ea + (size_t)e * EDIM);
    float d1 = 0.f, d2 = 0.f;
#pragma unroll
    for (int i = 0; i < 8; i++) {
        float4 v = ep[i];
        d1 += v.x * cs[4 * i] + v.y * cs[4 * i + 1] + v.z * cs[4 * i + 2] + v.w * cs[4 * i + 3];
        d2 += v.x * cs[32 + 4 * i] + v.y * cs[32 + 4 * i + 1] + v.z * cs[32 + 4 * i + 2] + v.w * cs[32 + 4 * i + 3];
    }
    dotv_p[ipos[e]] = make_float2(d1, d2);
    float s1 = d1, s2 = d2;
    for (int off = 32; off > 0; off >>= 1) {
        s1 += __shfl_down(s1, off, 64);
        s2 += __shfl_down(s2, off, 64);
    }
    if ((t & 63) == 0) {
        int slot = (blockIdx.x & 63) * 16;
        atomicAdd(&part[slot], s1);
        atomicAdd(&part[slot + 1], s2);
    }
}

__global__ void reduce_sdv_kernel(const float* __restrict__ part, float* __restrict__ sdv) {
    int t = threadIdx.x;   // 64 threads
    float s1 = part[t * 16], s2 = part[t * 16 + 1];
    for (int off = 32; off > 0; off >>= 1) {
        s1 += __shfl_down(s1, off, 64);
        s2 += __shfl_down(s2, off, 64);
    }
    if (t == 0) { sdv[0] = s1; sdv[1] = s2; }
}

// ---------------------------------------------------------------------------
// MFMA gemm: h = x @ W via bf16 split (xh+xl)@(Wh+Wl), dropping xl@Wl.
// One wave per 16-row tile; 4 waves/block. h stored row-major [N][128].
#define TILES_M (N_NODES / 16)                // 3125
#define GEMM_BLOCKS ((TILES_M + 3) / 4)       // 782
__global__ void __launch_bounds__(256)
gemm_mfma_kernel(const float* __restrict__ x,
                 const unsigned short* __restrict__ wh,
                 const unsigned short* __restrict__ wl,
                 const float* __restrict__ a_s, const float* __restrict__ a_d,
                 float* __restrict__ h, float* __restrict__ alpha,
                 float* __restrict__ beta) {
    int tile = blockIdx.x * 4 + (threadIdx.x >> 6);
    if (tile >= TILES_M) return;
    int l    = threadIdx.x & 63;
    int row0 = tile * 16;
    int arow = l & 15;            // A row / D col
    int kg   = l >> 4;            // k-group / D row-group
    bshort8 ah[4], al[4];
    const float* xr = x + (size_t)(row0 + arow) * HIDDEN + (kg << 3);
#pragma unroll
    for (int kc = 0; kc < 4; kc++) {
        float4 f0 = *(const float4*)(xr + kc * 32);
        float4 f1 = *(const float4*)(xr + kc * 32 + 4);
        float fv[8] = {f0.x, f0.y, f0.z, f0.w, f1.x, f1.y, f1.z, f1.w};
#pragma unroll
        for (int e = 0; e < 8; e++) {
            unsigned short hb = f2bf(fv[e]);
            ah[kc][e] = (short)hb;
            al[kc][e] = (short)f2bf(fv[e] - bf2f(hb));
        }
    }
    float pal[4] = {0.f, 0.f, 0.f, 0.f};
    float pbe[4] = {0.f, 0.f, 0.f, 0.f};
#pragma unroll
    for (int ct = 0; ct < 8; ct++) {
        f32x4 acc = {0.f, 0.f, 0.f, 0.f};
#pragma unroll
        for (int kc = 0; kc < 4; kc++) {
            int fo = (((ct * 4 + kc) * 64) + l) << 3;
            bshort8 bh = *(const bshort8*)(wh + fo);
            bshort8 bl = *(const bshort8*)(wl + fo);
            acc = __builtin_amdgcn_mfma_f32_16x16x32_bf16(ah[kc], bh, acc, 0, 0, 0);
            acc = __builtin_amdgcn_mfma_f32_16x16x32_bf16(al[kc], bh, acc, 0, 0, 0);
            acc = __builtin_amdgcn_mfma_f32_16x16x32_bf16(ah[kc], bl, acc, 0, 0, 0);
        }
        int col = ct * 16 + arow;
        float a_sc = a_s[col], a_dc = a_d[col];
#pragma unroll
        for (int j = 0; j < 4; j++) {
            h[(size_t)(row0 + kg * 4 + j) * HIDDEN + col] = acc[j];
            pal[j] += acc[j] * a_sc;
            pbe[j] += acc[j] * a_dc;
        }
    }
#pragma unroll
    for (int m = 1; m < 16; m <<= 1) {
#pragma unroll
        for (int j = 0; j < 4; j++) {
            pal[j] += __shfl_xor(pal[j], m, 64);
            pbe[j] += __shfl_xor(pbe[j], m, 64);
        }
    }
    if (arow == 0) {
#pragma unroll
        for (int j = 0; j < 4; j++) {
            alpha[row0 + kg * 4 + j] = pal[j];
            beta[row0 + kg * 4 + j]  = pbe[j];
        }
    }
}

// ---------------------------------------------------------------------------
// Gather-aggregate: ONE WAVE PER NODE (4 nodes / 256-block, no barriers).
// Lane l owns channels 2l, 2l+1 (float2). Edge weights computed inline;
// edge loop unrolled x4 with batched gathers for memory-level parallelism.
template<int LAYER, int FINAL>
__global__ void __launch_bounds__(256)
agg_kernel(const int* __restrict__ off_work,
           const int* __restrict__ src_p,
           const float2* __restrict__ dotv_p,
           const float* __restrict__ h,
           const float* __restrict__ alpha, const float* __restrict__ beta,
           const float* __restrict__ b, const float* __restrict__ sdv,
           const float* __restrict__ Wl, const float* __restrict__ bl,
           float* __restrict__ outp) {
    int t = threadIdx.x;
    int l = t & 63;
    int i = blockIdx.x * 4 + (t >> 6);
    int start = (i == 0) ? 0 : off_work[i - 1];
    int end   = off_work[i];
    float beta_i = beta[i];
    float2 acc = make_float2(0.f, 0.f);
    float wsum = 0.f;
    for (int cb = start; cb < end; cb += 64) {
        int n = min(64, end - cb);
        int sp = 0; float wt = 0.f;
        if (l < n) {
            sp = src_p[cb + l];
            float2 dv = dotv_p[cb + l];
            float lg = alpha[sp] + beta_i + (LAYER == 0 ? dv.x : dv.y);
            lg = lg > 0.f ? lg : NEG * lg;
            wt = expf(lg);
        }
        int j = 0;
        for (; j + 4 <= n; j += 4) {
            float w0 = __shfl(wt, j, 64),     w1 = __shfl(wt, j + 1, 64);
            float w2 = __shfl(wt, j + 2, 64), w3 = __shfl(wt, j + 3, 64);
            int s0 = __shfl(sp, j, 64),     s1 = __shfl(sp, j + 1, 64);
            int s2 = __shfl(sp, j + 2, 64), s3 = __shfl(sp, j + 3, 64);
            float2 h0 = ((const float2*)(h + (size_t)s0 * HIDDEN))[l];
            float2 h1 = ((const float2*)(h + (size_t)s1 * HIDDEN))[l];
            float2 h2 = ((const float2*)(h + (size_t)s2 * HIDDEN))[l];
            float2 h3 = ((const float2*)(h + (size_t)s3 * HIDDEN))[l];
            acc.x += w0 * h0.x; acc.y += w0 * h0.y;
            acc.x += w1 * h1.x; acc.y += w1 * h1.y;
            acc.x += w2 * h2.x; acc.y += w2 * h2.y;
            acc.x += w3 * h3.x; acc.y += w3 * h3.y;
            wsum += (w0 + w1) + (w2 + w3);
        }
        for (; j < n; j++) {
            float w = __shfl(wt, j, 64);
            int   sj = __shfl(sp, j, 64);
            float2 hv = ((const float2*)(h + (size_t)sj * HIDDEN))[l];
            acc.x += w * hv.x;
            acc.y += w * hv.y;
            wsum  += w;
        }
    }
    float selfc = sdv[LAYER] * (1.f / (float)N_EDGES);
    float lg = alpha[i] + beta_i + selfc;
    lg = lg > 0.f ? lg : NEG * lg;
    float exi = expf(lg);
    float denom = wsum + exi + 1e-16f;
    float2 hv = ((const float2*)(h + (size_t)i * HIDDEN))[l];
    float2 bb = ((const float2*)b)[l];
    float2 v;
    v.x = (acc.x + exi * hv.x) / denom + bb.x;
    v.y = (acc.y + exi * hv.y) / denom + bb.y;
    if (FINAL == 0) {
        ((float2*)(outp + (size_t)i * HIDDEN))[l] =
            make_float2(fmaxf(v.x, 0.f), fmaxf(v.y, 0.f));
    } else {
        float2 wl = ((const float2*)Wl)[l];
        float contrib = v.x * wl.x + v.y * wl.y;
        for (int off = 32; off > 0; off >>= 1) contrib += __shfl_down(contrib, off, 64);
        if (l == 0) outp[i] = fmaxf(contrib + bl[0], 0.f);
    }
}

// ---------------------------------------------------------------------------
extern "C" void kernel_launch(void* const* d_in, const int* in_sizes, int n_in,
                              void* d_out, int out_size, void* d_ws, size_t ws_size,
                              hipStream_t stream) {
    const float* x   = (const float*)d_in[0];
    const int*   src = (const int*)  d_in[1];
    const int*   dst = (const int*)  d_in[2];
    const float* ea  = (const float*)d_in[3];
    const float* W1  = (const float*)d_in[4];
    const float* We1 = (const float*)d_in[5];
    const float* as1 = (const float*)d_in[6];
    const float* ad1 = (const float*)d_in[7];
    const float* ae1 = (const float*)d_in[8];
    const float* b1  = (const float*)d_in[9];
    const float* W2  = (const float*)d_in[10];
    const float* We2 = (const float*)d_in[11];
    const float* as2 = (const float*)d_in[12];
    const float* ad2 = (const float*)d_in[13];
    const float* ae2 = (const float*)d_in[14];
    const float* b2  = (const float*)d_in[15];
    const float* Wl  = (const float*)d_in[16];
    const float* bl  = (const float*)d_in[17];
    float* out = (float*)d_out;

    float* ws      = (float*)d_ws;
    float* A       = ws;                           // [N*128]  h1, then h2
    float* B       = A + (size_t)N_NODES * HIDDEN; // [N*128]  out1 (conv1 result)
    unsigned short* whp1 = (unsigned short*)(B + (size_t)N_NODES * HIDDEN);
    unsigned short* wlp1 = whp1 + 16384;
    unsigned short* whp2 = wlp1 + 16384;
    unsigned short* wlp2 = whp2 + 16384;
    float* alpha   = (float*)(wlp2 + 16384);       // [N]
    float* beta    = alpha + N_NODES;              // [N]
    float2* dotv_p = (float2*)(beta + N_NODES);    // [E] (d1,d2) dst-sorted
    float* consts  = (float*)(dotv_p + N_EDGES);   // [64] ce1, ce2
    float* part    = consts + 64;                  // [64*16] padded partials
    float* sdv     = part + 64 * 16;               // [2]
    int* count     = (int*)(sdv + 2);              // [N]
    int* off_work  = count + N_NODES;              // [N]
    int* blocksum  = off_work + N_NODES;           // [SCAN_BLOCKS]
    int* blockoff  = blocksum + SCAN_BLOCKS;       // [SCAN_BLOCKS]
    int* src_p     = blockoff + SCAN_BLOCKS;       // [E] dst-sorted src ids
    int* ipos      = src_p + N_EDGES;              // [E] edge -> sorted slot

    const int EB = (N_EDGES + 255) / 256;

    // ---- prep: constants, W frag pack, CSR build, ea pass ----
    hipMemsetAsync(count, 0, N_NODES * sizeof(int), stream);
    hipMemsetAsync(part, 0, 64 * 16 * sizeof(float), stream);
    prep_kernel<<<1, 64, 0, stream>>>(We1, ae1, We2, ae2, consts);
    pack_w_kernel<<<64, 256, 0, stream>>>(W1, whp1, wlp1);
    pack_w_kernel<<<64, 256, 0, stream>>>(W2, whp2, wlp2);
    hist_kernel<<<EB, 256, 0, stream>>>(dst, count);
    scan1_kernel<<<SCAN_BLOCKS, 256, 0, stream>>>(count, off_work, blocksum);
    scan2_kernel<<<1, 256, 0, stream>>>(blocksum, blockoff);
    scan3_kernel<<<SCAN_BLOCKS, 256, 0, stream>>>(off_work, blockoff);
    scatter_kernel<<<EB, 256, 0, stream>>>(src, dst, off_work, src_p, ipos);
    dotv_kernel<<<EB, 256, 0, stream>>>(ea, consts, ipos, dotv_p, part);
    reduce_sdv_kernel<<<1, 64, 0, stream>>>(part, sdv);

    // ---- conv1 ----
    gemm_mfma_kernel<<<GEMM_BLOCKS, 256, 0, stream>>>(x, whp1, wlp1, as1, ad1,
                                                      A, alpha, beta);
    agg_kernel<0, 0><<<N_NODES / 4, 256, 0, stream>>>(off_work, src_p, dotv_p, A, alpha, beta,
                                                      b1, sdv, nullptr, nullptr, B);

    // ---- conv2 (+ final linear fused) ----
    gemm_mfma_kernel<<<GEMM_BLOCKS, 256, 0, stream>>>(B, whp2, wlp2, as2, ad2,
                                                      A, alpha, beta);
    agg_kernel<1, 1><<<N_NODES / 4, 256, 0, stream>>>(off_work, src_p, dotv_p, A, alpha, beta,
                                                      b2, sdv, Wl, bl, out);
}

// Round 11
// 269.426 us; speedup vs baseline: 2.1400x; 1.1323x over previous
//
#include <hip/hip_runtime.h>
#include <math.h>

#define N_NODES 50000
#define N_EDGES 800000
#define HIDDEN  128
#define EDIM    32
#define NEG     0.2f

typedef __attribute__((ext_vector_type(8))) short bshort8;
typedef __attribute__((ext_vector_type(4))) float f32x4;

__device__ __forceinline__ unsigned short f2bf(float f) {
    unsigned u = __builtin_bit_cast(unsigned, f);
    return (unsigned short)((u + 0x7FFFu + ((u >> 16) & 1u)) >> 16);
}
__device__ __forceinline__ float bf2f(unsigned short b) {
    unsigned u = ((unsigned)b) << 16;
    return __builtin_bit_cast(float, u);
}

// ---------------------------------------------------------------------------
// ce1 = We1 @ ae1, ce2 = We2 @ ae2 (each [32])
__global__ void prep_kernel(const float* __restrict__ We1, const float* __restrict__ ae1,
                            const float* __restrict__ We2, const float* __restrict__ ae2,
                            float* __restrict__ consts) {
    int t = threadIdx.x;
    if (t < 32) {
        float acc = 0.f;
        for (int k = 0; k < HIDDEN; k++) acc += We1[t * HIDDEN + k] * ae1[k];
        consts[t] = acc;
    } else if (t < 64) {
        int j = t - 32;
        float acc = 0.f;
        for (int k = 0; k < HIDDEN; k++) acc += We2[j * HIDDEN + k] * ae2[k];
        consts[32 + j] = acc;
    }
}

// ---------------------------------------------------------------------------
// Pack W (128x128 row-major, [k][col]) into MFMA B-fragment order, bf16 split.
__global__ void pack_w_kernel(const float* __restrict__ W,
                              unsigned short* __restrict__ whp,
                              unsigned short* __restrict__ wlp) {
    int idx = blockIdx.x * 256 + threadIdx.x;   // 16384 total
    int e  = idx & 7;
    int l  = (idx >> 3) & 63;
    int kc = (idx >> 9) & 3;
    int ct = (idx >> 11);
    int k   = kc * 32 + ((l >> 4) << 3) + e;
    int col = ct * 16 + (l & 15);
    float w = W[k * HIDDEN + col];
    unsigned short hb = f2bf(w);
    whp[idx] = hb;
    wlp[idx] = f2bf(w - bf2f(hb));
}

// ---------------------------------------------------------------------------
// CSR build
__global__ void hist_kernel(const int* __restrict__ dst, int* __restrict__ count) {
    int e = blockIdx.x * blockDim.x + threadIdx.x;
    if (e < N_EDGES) atomicAdd(&count[dst[e]], 1);
}

#define SCAN_BLOCKS ((N_NODES + 255) / 256)   // 196
__global__ void scan1_kernel(const int* __restrict__ count,
                             int* __restrict__ off_work, int* __restrict__ blocksum) {
    __shared__ int sh[256];
    int t = threadIdx.x;
    int idx = blockIdx.x * 256 + t;
    int v = (idx < N_NODES) ? count[idx] : 0;
    sh[t] = v;
    __syncthreads();
    for (int off = 1; off < 256; off <<= 1) {
        int u = (t >= off) ? sh[t - off] : 0;
        __syncthreads();
        sh[t] += u;
        __syncthreads();
    }
    if (idx < N_NODES) off_work[idx] = sh[t] - v;
    if (t == 255) blocksum[blockIdx.x] = sh[255];
}
__global__ void scan2_kernel(int* __restrict__ blocksum, int* __restrict__ blockoff) {
    __shared__ int sh[256];
    int t = threadIdx.x;
    int v = (t < SCAN_BLOCKS) ? blocksum[t] : 0;
    sh[t] = v;
    __syncthreads();
    for (int off = 1; off < 256; off <<= 1) {
        int u = (t >= off) ? sh[t - off] : 0;
        __syncthreads();
        sh[t] += u;
        __syncthreads();
    }
    if (t < SCAN_BLOCKS) blockoff[t] = sh[t] - v;
}
__global__ void scan3_kernel(int* __restrict__ off_work, const int* __restrict__ blockoff) {
    int idx = blockIdx.x * 256 + threadIdx.x;
    if (idx < N_NODES) off_work[idx] += blockoff[blockIdx.x];
}

// ---------------------------------------------------------------------------
// FUSED CSR-scatter + edge-scalar pass (one coalesced ea read):
//   d1 = ea_e . ce1 ; d2 = ea_e . ce2
//   pos = cursor atomic on off_work[dst]; src_p[pos]=src; dotv_p[pos]=(d1,d2)
// Also accumulates sums of d1,d2 into 64 padded partial slots.
// After: off_work[i] == end offset of segment i; off_work[i-1] == start.
__global__ void scatter_dotv_kernel(const int* __restrict__ src, const int* __restrict__ dst,
                                    const float* __restrict__ ea,
                                    const float* __restrict__ consts,
                                    int* __restrict__ off_work,
                                    int* __restrict__ src_p, float2* __restrict__ dotv_p,
                                    float* __restrict__ part) {
    __shared__ float cs[64];
    int t = threadIdx.x;
    if (t < 64) cs[t] = consts[t];
    __syncthreads();
    int e = blockIdx.x * blockDim.x + t;   // N_EDGES % 256 == 0
    const float4* ep = (const float4*)(ea + (size_t)e * EDIM);
    float d1 = 0.f, d2 = 0.f;
#pragma unroll
    for (int i = 0; i < 8; i++) {
        float4 v = ep[i];
        d1 += v.x * cs[4 * i] + v.y * cs[4 * i + 1] + v.z * cs[4 * i + 2] + v.w * cs[4 * i + 3];
        d2 += v.x * cs[32 + 4 * i] + v.y * cs[32 + 4 * i + 1] + v.z * cs[32 + 4 * i + 2] + v.w * cs[32 + 4 * i + 3];
    }
    int pos = atomicAdd(&off_work[dst[e]], 1);
    src_p[pos] = src[e];
    dotv_p[pos] = make_float2(d1, d2);
    float s1 = d1, s2 = d2;
    for (int off = 32; off > 0; off >>= 1) {
        s1 += __shfl_down(s1, off, 64);
        s2 += __shfl_down(s2, off, 64);
    }
    if ((t & 63) == 0) {
        int slot = (blockIdx.x & 63) * 16;
        atomicAdd(&part[slot], s1);
        atomicAdd(&part[slot + 1], s2);
    }
}

__global__ void reduce_sdv_kernel(const float* __restrict__ part, float* __restrict__ sdv) {
    int t = threadIdx.x;   // 64 threads
    float s1 = part[t * 16], s2 = part[t * 16 + 1];
    for (int off = 32; off > 0; off >>= 1) {
        s1 += __shfl_down(s1, off, 64);
        s2 += __shfl_down(s2, off, 64);
    }
    if (t == 0) { sdv[0] = s1; sdv[1] = s2; }
}

// ---------------------------------------------------------------------------
// MFMA gemm: h = x @ W via bf16 split (xh+xl)@(Wh+Wl), dropping xl@Wl.
// One wave per 16-row tile; 4 waves/block. h stored row-major [N][128].
#define TILES_M (N_NODES / 16)                // 3125
#define GEMM_BLOCKS ((TILES_M + 3) / 4)       // 782
__global__ void __launch_bounds__(256)
gemm_mfma_kernel(const float* __restrict__ x,
                 const unsigned short* __restrict__ wh,
                 const unsigned short* __restrict__ wl,
                 const float* __restrict__ a_s, const float* __restrict__ a_d,
                 float* __restrict__ h, float* __restrict__ alpha,
                 float* __restrict__ beta) {
    int tile = blockIdx.x * 4 + (threadIdx.x >> 6);
    if (tile >= TILES_M) return;
    int l    = threadIdx.x & 63;
    int row0 = tile * 16;
    int arow = l & 15;            // A row / D col
    int kg   = l >> 4;            // k-group / D row-group
    bshort8 ah[4], al[4];
    const float* xr = x + (size_t)(row0 + arow) * HIDDEN + (kg << 3);
#pragma unroll
    for (int kc = 0; kc < 4; kc++) {
        float4 f0 = *(const float4*)(xr + kc * 32);
        float4 f1 = *(const float4*)(xr + kc * 32 + 4);
        float fv[8] = {f0.x, f0.y, f0.z, f0.w, f1.x, f1.y, f1.z, f1.w};
#pragma unroll
        for (int e = 0; e < 8; e++) {
            unsigned short hb = f2bf(fv[e]);
            ah[kc][e] = (short)hb;
            al[kc][e] = (short)f2bf(fv[e] - bf2f(hb));
        }
    }
    float pal[4] = {0.f, 0.f, 0.f, 0.f};
    float pbe[4] = {0.f, 0.f, 0.f, 0.f};
#pragma unroll
    for (int ct = 0; ct < 8; ct++) {
        f32x4 acc = {0.f, 0.f, 0.f, 0.f};
#pragma unroll
        for (int kc = 0; kc < 4; kc++) {
            int fo = (((ct * 4 + kc) * 64) + l) << 3;
            bshort8 bh = *(const bshort8*)(wh + fo);
            bshort8 bl = *(const bshort8*)(wl + fo);
            acc = __builtin_amdgcn_mfma_f32_16x16x32_bf16(ah[kc], bh, acc, 0, 0, 0);
            acc = __builtin_amdgcn_mfma_f32_16x16x32_bf16(al[kc], bh, acc, 0, 0, 0);
            acc = __builtin_amdgcn_mfma_f32_16x16x32_bf16(ah[kc], bl, acc, 0, 0, 0);
        }
        int col = ct * 16 + arow;
        float a_sc = a_s[col], a_dc = a_d[col];
#pragma unroll
        for (int j = 0; j < 4; j++) {
            h[(size_t)(row0 + kg * 4 + j) * HIDDEN + col] = acc[j];
            pal[j] += acc[j] * a_sc;
            pbe[j] += acc[j] * a_dc;
        }
    }
#pragma unroll
    for (int m = 1; m < 16; m <<= 1) {
#pragma unroll
        for (int j = 0; j < 4; j++) {
            pal[j] += __shfl_xor(pal[j], m, 64);
            pbe[j] += __shfl_xor(pbe[j], m, 64);
        }
    }
    if (arow == 0) {
#pragma unroll
        for (int j = 0; j < 4; j++) {
            alpha[row0 + kg * 4 + j] = pal[j];
            beta[row0 + kg * 4 + j]  = pbe[j];
        }
    }
}

// ---------------------------------------------------------------------------
// Gather-aggregate: ONE WAVE PER NODE (4 nodes / 256-block, no barriers).
// Lane l owns channels 2l, 2l+1 (float2). Edge weights computed inline;
// edge loop unrolled x8/x4 with batched gathers for memory-level parallelism.
template<int LAYER, int FINAL>
__global__ void __launch_bounds__(256)
agg_kernel(const int* __restrict__ off_work,
           const int* __restrict__ src_p,
           const float2* __restrict__ dotv_p,
           const float* __restrict__ h,
           const float* __restrict__ alpha, const float* __restrict__ beta,
           const float* __restrict__ b, const float* __restrict__ sdv,
           const float* __restrict__ Wl, const float* __restrict__ bl,
           float* __restrict__ outp) {
    int t = threadIdx.x;
    int l = t & 63;
    int i = blockIdx.x * 4 + (t >> 6);
    int start = (i == 0) ? 0 : off_work[i - 1];
    int end   = off_work[i];
    float beta_i = beta[i];
    float2 acc = make_float2(0.f, 0.f);
    float wsum = 0.f;
    for (int cb = start; cb < end; cb += 64) {
        int n = min(64, end - cb);
        int sp = 0; float wt = 0.f;
        if (l < n) {
            sp = src_p[cb + l];
            float2 dv = dotv_p[cb + l];
            float lg = alpha[sp] + beta_i + (LAYER == 0 ? dv.x : dv.y);
            lg = lg > 0.f ? lg : NEG * lg;
            wt = expf(lg);
        }
        int j = 0;
        for (; j + 8 <= n; j += 8) {
            float w8[8]; int s8[8]; float2 h8[8];
#pragma unroll
            for (int q = 0; q < 8; q++) {
                w8[q] = __shfl(wt, j + q, 64);
                s8[q] = __shfl(sp, j + q, 64);
            }
#pragma unroll
            for (int q = 0; q < 8; q++)
                h8[q] = ((const float2*)(h + (size_t)s8[q] * HIDDEN))[l];
#pragma unroll
            for (int q = 0; q < 8; q++) {
                acc.x += w8[q] * h8[q].x;
                acc.y += w8[q] * h8[q].y;
                wsum  += w8[q];
            }
        }
        for (; j + 4 <= n; j += 4) {
            float w4[4]; int s4[4]; float2 h4[4];
#pragma unroll
            for (int q = 0; q < 4; q++) {
                w4[q] = __shfl(wt, j + q, 64);
                s4[q] = __shfl(sp, j + q, 64);
            }
#pragma unroll
            for (int q = 0; q < 4; q++)
                h4[q] = ((const float2*)(h + (size_t)s4[q] * HIDDEN))[l];
#pragma unroll
            for (int q = 0; q < 4; q++) {
                acc.x += w4[q] * h4[q].x;
                acc.y += w4[q] * h4[q].y;
                wsum  += w4[q];
            }
        }
        for (; j < n; j++) {
            float w = __shfl(wt, j, 64);
            int   sj = __shfl(sp, j, 64);
            float2 hv = ((const float2*)(h + (size_t)sj * HIDDEN))[l];
            acc.x += w * hv.x;
            acc.y += w * hv.y;
            wsum  += w;
        }
    }
    float selfc = sdv[LAYER] * (1.f / (float)N_EDGES);
    float lg = alpha[i] + beta_i + selfc;
    lg = lg > 0.f ? lg : NEG * lg;
    float exi = expf(lg);
    float denom = wsum + exi + 1e-16f;
    float2 hv = ((const float2*)(h + (size_t)i * HIDDEN))[l];
    float2 bb = ((const float2*)b)[l];
    float2 v;
    v.x = (acc.x + exi * hv.x) / denom + bb.x;
    v.y = (acc.y + exi * hv.y) / denom + bb.y;
    if (FINAL == 0) {
        ((float2*)(outp + (size_t)i * HIDDEN))[l] =
            make_float2(fmaxf(v.x, 0.f), fmaxf(v.y, 0.f));
    } else {
        float2 wl = ((const float2*)Wl)[l];
        float contrib = v.x * wl.x + v.y * wl.y;
        for (int off = 32; off > 0; off >>= 1) contrib += __shfl_down(contrib, off, 64);
        if (l == 0) outp[i] = fmaxf(contrib + bl[0], 0.f);
    }
}

// ---------------------------------------------------------------------------
extern "C" void kernel_launch(void* const* d_in, const int* in_sizes, int n_in,
                              void* d_out, int out_size, void* d_ws, size_t ws_size,
                              hipStream_t stream) {
    const float* x   = (const float*)d_in[0];
    const int*   src = (const int*)  d_in[1];
    const int*   dst = (const int*)  d_in[2];
    const float* ea  = (const float*)d_in[3];
    const float* W1  = (const float*)d_in[4];
    const float* We1 = (const float*)d_in[5];
    const float* as1 = (const float*)d_in[6];
    const float* ad1 = (const float*)d_in[7];
    const float* ae1 = (const float*)d_in[8];
    const float* b1  = (const float*)d_in[9];
    const float* W2  = (const float*)d_in[10];
    const float* We2 = (const float*)d_in[11];
    const float* as2 = (const float*)d_in[12];
    const float* ad2 = (const float*)d_in[13];
    const float* ae2 = (const float*)d_in[14];
    const float* b2  = (const float*)d_in[15];
    const float* Wl  = (const float*)d_in[16];
    const float* bl  = (const float*)d_in[17];
    float* out = (float*)d_out;

    float* ws      = (float*)d_ws;
    float* A       = ws;                           // [N*128]  h1, then h2
    float* B       = A + (size_t)N_NODES * HIDDEN; // [N*128]  out1 (conv1 result)
    unsigned short* whp1 = (unsigned short*)(B + (size_t)N_NODES * HIDDEN);
    unsigned short* wlp1 = whp1 + 16384;
    unsigned short* whp2 = wlp1 + 16384;
    unsigned short* wlp2 = whp2 + 16384;
    float* alpha   = (float*)(wlp2 + 16384);       // [N]
    float* beta    = alpha + N_NODES;              // [N]
    float2* dotv_p = (float2*)(beta + N_NODES);    // [E] (d1,d2) dst-sorted
    float* consts  = (float*)(dotv_p + N_EDGES);   // [64] ce1, ce2
    float* part    = consts + 64;                  // [64*16] padded partials
    float* sdv     = part + 64 * 16;               // [2]
    int* count     = (int*)(sdv + 2);              // [N]
    int* off_work  = count + N_NODES;              // [N]
    int* blocksum  = off_work + N_NODES;           // [SCAN_BLOCKS]
    int* blockoff  = blocksum + SCAN_BLOCKS;       // [SCAN_BLOCKS]
    int* src_p     = blockoff + SCAN_BLOCKS;       // [E] dst-sorted src ids

    const int EB = (N_EDGES + 255) / 256;

    // ---- prep: constants, W frag pack, CSR build fused with ea pass ----
    hipMemsetAsync(count, 0, N_NODES * sizeof(int), stream);
    hipMemsetAsync(part, 0, 64 * 16 * sizeof(float), stream);
    prep_kernel<<<1, 64, 0, stream>>>(We1, ae1, We2, ae2, consts);
    pack_w_kernel<<<64, 256, 0, stream>>>(W1, whp1, wlp1);
    pack_w_kernel<<<64, 256, 0, stream>>>(W2, whp2, wlp2);
    hist_kernel<<<EB, 256, 0, stream>>>(dst, count);
    scan1_kernel<<<SCAN_BLOCKS, 256, 0, stream>>>(count, off_work, blocksum);
    scan2_kernel<<<1, 256, 0, stream>>>(blocksum, blockoff);
    scan3_kernel<<<SCAN_BLOCKS, 256, 0, stream>>>(off_work, blockoff);
    scatter_dotv_kernel<<<EB, 256, 0, stream>>>(src, dst, ea, consts, off_work,
                                                src_p, dotv_p, part);
    reduce_sdv_kernel<<<1, 64, 0, stream>>>(part, sdv);

    // ---- conv1 ----
    gemm_mfma_kernel<<<GEMM_BLOCKS, 256, 0, stream>>>(x, whp1, wlp1, as1, ad1,
                                                      A, alpha, beta);
    agg_kernel<0, 0><<<N_NODES / 4, 256, 0, stream>>>(off_work, src_p, dotv_p, A, alpha, beta,
                                                      b1, sdv, nullptr, nullptr, B);

    // ---- conv2 (+ final linear fused) ----
    gemm_mfma_kernel<<<GEMM_BLOCKS, 256, 0, stream>>>(B, whp2, wlp2, as2, ad2,
                                                      A, alpha, beta);
    agg_kernel<1, 1><<<N_NODES / 4, 256, 0, stream>>>(off_work, src_p, dotv_p, A, alpha, beta,
                                                      b2, sdv, Wl, bl, out);
}

// Round 12
// 267.366 us; speedup vs baseline: 2.1565x; 1.0077x over previous
//
#include <hip/hip_runtime.h>
#include <math.h>

#define N_NODES 50000
#define N_EDGES 800000
#define HIDDEN  128
#define EDIM    32
#define NEG     0.2f

typedef __attribute__((ext_vector_type(8))) short bshort8;
typedef __attribute__((ext_vector_type(4))) float f32x4;

__device__ __forceinline__ unsigned short f2bf(float f) {
    unsigned u = __builtin_bit_cast(unsigned, f);
    return (unsigned short)((u + 0x7FFFu + ((u >> 16) & 1u)) >> 16);
}
__device__ __forceinline__ float bf2f(unsigned short b) {
    unsigned u = ((unsigned)b) << 16;
    return __builtin_bit_cast(float, u);
}

// ---------------------------------------------------------------------------
// ce1 = We1 @ ae1, ce2 = We2 @ ae2 (each [32])
__global__ void prep_kernel(const float* __restrict__ We1, const float* __restrict__ ae1,
                            const float* __restrict__ We2, const float* __restrict__ ae2,
                            float* __restrict__ consts) {
    int t = threadIdx.x;
    if (t < 32) {
        float acc = 0.f;
        for (int k = 0; k < HIDDEN; k++) acc += We1[t * HIDDEN + k] * ae1[k];
        consts[t] = acc;
    } else if (t < 64) {
        int j = t - 32;
        float acc = 0.f;
        for (int k = 0; k < HIDDEN; k++) acc += We2[j * HIDDEN + k] * ae2[k];
        consts[32 + j] = acc;
    }
}

// ---------------------------------------------------------------------------
// Pack W (128x128 row-major, [k][col]) into MFMA B-fragment order, bf16 split.
__global__ void pack_w_kernel(const float* __restrict__ W,
                              unsigned short* __restrict__ whp,
                              unsigned short* __restrict__ wlp) {
    int idx = blockIdx.x * 256 + threadIdx.x;   // 16384 total
    int e  = idx & 7;
    int l  = (idx >> 3) & 63;
    int kc = (idx >> 9) & 3;
    int ct = (idx >> 11);
    int k   = kc * 32 + ((l >> 4) << 3) + e;
    int col = ct * 16 + (l & 15);
    float w = W[k * HIDDEN + col];
    unsigned short hb = f2bf(w);
    whp[idx] = hb;
    wlp[idx] = f2bf(w - bf2f(hb));
}

// ---------------------------------------------------------------------------
// CSR build
__global__ void hist_kernel(const int* __restrict__ dst, int* __restrict__ count) {
    int e = blockIdx.x * blockDim.x + threadIdx.x;
    if (e < N_EDGES) atomicAdd(&count[dst[e]], 1);
}

#define SCAN_BLOCKS ((N_NODES + 255) / 256)   // 196
__global__ void scan1_kernel(const int* __restrict__ count,
                             int* __restrict__ off_work, int* __restrict__ blocksum) {
    __shared__ int sh[256];
    int t = threadIdx.x;
    int idx = blockIdx.x * 256 + t;
    int v = (idx < N_NODES) ? count[idx] : 0;
    sh[t] = v;
    __syncthreads();
    for (int off = 1; off < 256; off <<= 1) {
        int u = (t >= off) ? sh[t - off] : 0;
        __syncthreads();
        sh[t] += u;
        __syncthreads();
    }
    if (idx < N_NODES) off_work[idx] = sh[t] - v;
    if (t == 255) blocksum[blockIdx.x] = sh[255];
}
__global__ void scan2_kernel(int* __restrict__ blocksum, int* __restrict__ blockoff) {
    __shared__ int sh[256];
    int t = threadIdx.x;
    int v = (t < SCAN_BLOCKS) ? blocksum[t] : 0;
    sh[t] = v;
    __syncthreads();
    for (int off = 1; off < 256; off <<= 1) {
        int u = (t >= off) ? sh[t - off] : 0;
        __syncthreads();
        sh[t] += u;
        __syncthreads();
    }
    if (t < SCAN_BLOCKS) blockoff[t] = sh[t] - v;
}
__global__ void scan3_kernel(int* __restrict__ off_work, const int* __restrict__ blockoff) {
    int idx = blockIdx.x * 256 + threadIdx.x;
    if (idx < N_NODES) off_work[idx] += blockoff[blockIdx.x];
}

// ---------------------------------------------------------------------------
// FUSED CSR-scatter + edge-scalar pass, PACKED 16B record, 2 edges/thread:
//   erec[pos] = {d1, d2, bitcast(src), 0}
// Also accumulates sums of d1,d2 into 64 padded partial slots.
// After: off_work[i] == end offset of segment i; off_work[i-1] == start.
__global__ void scatter_dotv_kernel(const int* __restrict__ src, const int* __restrict__ dst,
                                    const float* __restrict__ ea,
                                    const float* __restrict__ consts,
                                    int* __restrict__ off_work,
                                    float4* __restrict__ erec,
                                    float* __restrict__ part) {
    __shared__ float cs[64];
    int t = threadIdx.x;
    if (t < 64) cs[t] = consts[t];
    __syncthreads();
    int e0 = blockIdx.x * 512 + t;
    int e1 = e0 + 256;
    float sd1 = 0.f, sd2 = 0.f;
#pragma unroll
    for (int half = 0; half < 2; half++) {
        int e = half ? e1 : e0;
        if (e < N_EDGES) {
            const float4* ep = (const float4*)(ea + (size_t)e * EDIM);
            float d1 = 0.f, d2 = 0.f;
#pragma unroll
            for (int i = 0; i < 8; i++) {
                float4 v = ep[i];
                d1 += v.x * cs[4 * i] + v.y * cs[4 * i + 1] + v.z * cs[4 * i + 2] + v.w * cs[4 * i + 3];
                d2 += v.x * cs[32 + 4 * i] + v.y * cs[32 + 4 * i + 1] + v.z * cs[32 + 4 * i + 2] + v.w * cs[32 + 4 * i + 3];
            }
            int pos = atomicAdd(&off_work[dst[e]], 1);
            erec[pos] = make_float4(d1, d2, __int_as_float(src[e]), 0.f);
            sd1 += d1; sd2 += d2;
        }
    }
    for (int off = 32; off > 0; off >>= 1) {
        sd1 += __shfl_down(sd1, off, 64);
        sd2 += __shfl_down(sd2, off, 64);
    }
    if ((t & 63) == 0) {
        int slot = (blockIdx.x & 63) * 16;
        atomicAdd(&part[slot], sd1);
        atomicAdd(&part[slot + 1], sd2);
    }
}

__global__ void reduce_sdv_kernel(const float* __restrict__ part, float* __restrict__ sdv) {
    int t = threadIdx.x;   // 64 threads
    float s1 = part[t * 16], s2 = part[t * 16 + 1];
    for (int off = 32; off > 0; off >>= 1) {
        s1 += __shfl_down(s1, off, 64);
        s2 += __shfl_down(s2, off, 64);
    }
    if (t == 0) { sdv[0] = s1; sdv[1] = s2; }
}

// ---------------------------------------------------------------------------
// MFMA gemm: h = x @ W via bf16 split (xh+xl)@(Wh+Wl), dropping xl@Wl.
// One wave per 16-row tile; 4 waves/block. h stored row-major [N][128].
#define TILES_M (N_NODES / 16)                // 3125
#define GEMM_BLOCKS ((TILES_M + 3) / 4)       // 782
__global__ void __launch_bounds__(256)
gemm_mfma_kernel(const float* __restrict__ x,
                 const unsigned short* __restrict__ wh,
                 const unsigned short* __restrict__ wl,
                 const float* __restrict__ a_s, const float* __restrict__ a_d,
                 float* __restrict__ h, float* __restrict__ alpha,
                 float* __restrict__ beta) {
    int tile = blockIdx.x * 4 + (threadIdx.x >> 6);
    if (tile >= TILES_M) return;
    int l    = threadIdx.x & 63;
    int row0 = tile * 16;
    int arow = l & 15;            // A row / D col
    int kg   = l >> 4;            // k-group / D row-group
    bshort8 ah[4], al[4];
    const float* xr = x + (size_t)(row0 + arow) * HIDDEN + (kg << 3);
#pragma unroll
    for (int kc = 0; kc < 4; kc++) {
        float4 f0 = *(const float4*)(xr + kc * 32);
        float4 f1 = *(const float4*)(xr + kc * 32 + 4);
        float fv[8] = {f0.x, f0.y, f0.z, f0.w, f1.x, f1.y, f1.z, f1.w};
#pragma unroll
        for (int e = 0; e < 8; e++) {
            unsigned short hb = f2bf(fv[e]);
            ah[kc][e] = (short)hb;
            al[kc][e] = (short)f2bf(fv[e] - bf2f(hb));
        }
    }
    float pal[4] = {0.f, 0.f, 0.f, 0.f};
    float pbe[4] = {0.f, 0.f, 0.f, 0.f};
#pragma unroll
    for (int ct = 0; ct < 8; ct++) {
        f32x4 acc = {0.f, 0.f, 0.f, 0.f};
#pragma unroll
        for (int kc = 0; kc < 4; kc++) {
            int fo = (((ct * 4 + kc) * 64) + l) << 3;
            bshort8 bh = *(const bshort8*)(wh + fo);
            bshort8 bl = *(const bshort8*)(wl + fo);
            acc = __builtin_amdgcn_mfma_f32_16x16x32_bf16(ah[kc], bh, acc, 0, 0, 0);
            acc = __builtin_amdgcn_mfma_f32_16x16x32_bf16(al[kc], bh, acc, 0, 0, 0);
            acc = __builtin_amdgcn_mfma_f32_16x16x32_bf16(ah[kc], bl, acc, 0, 0, 0);
        }
        int col = ct * 16 + arow;
        float a_sc = a_s[col], a_dc = a_d[col];
#pragma unroll
        for (int j = 0; j < 4; j++) {
            h[(size_t)(row0 + kg * 4 + j) * HIDDEN + col] = acc[j];
            pal[j] += acc[j] * a_sc;
            pbe[j] += acc[j] * a_dc;
        }
    }
#pragma unroll
    for (int m = 1; m < 16; m <<= 1) {
#pragma unroll
        for (int j = 0; j < 4; j++) {
            pal[j] += __shfl_xor(pal[j], m, 64);
            pbe[j] += __shfl_xor(pbe[j], m, 64);
        }
    }
    if (arow == 0) {
#pragma unroll
        for (int j = 0; j < 4; j++) {
            alpha[row0 + kg * 4 + j] = pal[j];
            beta[row0 + kg * 4 + j]  = pbe[j];
        }
    }
}

// ---------------------------------------------------------------------------
// Gather-aggregate: ONE WAVE PER NODE (4 nodes / 256-block, no barriers).
// Lane l owns channels 2l, 2l+1 (float2). Edge record = packed float4.
// Edge loop unrolled x8/x4 with batched gathers for memory-level parallelism.
template<int LAYER, int FINAL>
__global__ void __launch_bounds__(256)
agg_kernel(const int* __restrict__ off_work,
           const float4* __restrict__ erec,
           const float* __restrict__ h,
           const float* __restrict__ alpha, const float* __restrict__ beta,
           const float* __restrict__ b, const float* __restrict__ sdv,
           const float* __restrict__ Wl, const float* __restrict__ bl,
           float* __restrict__ outp) {
    int t = threadIdx.x;
    int l = t & 63;
    int i = blockIdx.x * 4 + (t >> 6);
    int start = (i == 0) ? 0 : off_work[i - 1];
    int end   = off_work[i];
    float beta_i = beta[i];
    float2 acc = make_float2(0.f, 0.f);
    float wsum = 0.f;
    for (int cb = start; cb < end; cb += 64) {
        int n = min(64, end - cb);
        int sp = 0; float wt = 0.f;
        if (l < n) {
            float4 rec = erec[cb + l];
            sp = __float_as_int(rec.z);
            float lg = alpha[sp] + beta_i + (LAYER == 0 ? rec.x : rec.y);
            lg = lg > 0.f ? lg : NEG * lg;
            wt = expf(lg);
        }
        int j = 0;
        for (; j + 8 <= n; j += 8) {
            float w8[8]; int s8[8]; float2 h8[8];
#pragma unroll
            for (int q = 0; q < 8; q++) {
                w8[q] = __shfl(wt, j + q, 64);
                s8[q] = __shfl(sp, j + q, 64);
            }
#pragma unroll
            for (int q = 0; q < 8; q++)
                h8[q] = ((const float2*)(h + (size_t)s8[q] * HIDDEN))[l];
#pragma unroll
            for (int q = 0; q < 8; q++) {
                acc.x += w8[q] * h8[q].x;
                acc.y += w8[q] * h8[q].y;
                wsum  += w8[q];
            }
        }
        for (; j + 4 <= n; j += 4) {
            float w4[4]; int s4[4]; float2 h4[4];
#pragma unroll
            for (int q = 0; q < 4; q++) {
                w4[q] = __shfl(wt, j + q, 64);
                s4[q] = __shfl(sp, j + q, 64);
            }
#pragma unroll
            for (int q = 0; q < 4; q++)
                h4[q] = ((const float2*)(h + (size_t)s4[q] * HIDDEN))[l];
#pragma unroll
            for (int q = 0; q < 4; q++) {
                acc.x += w4[q] * h4[q].x;
                acc.y += w4[q] * h4[q].y;
                wsum  += w4[q];
            }
        }
        for (; j < n; j++) {
            float w = __shfl(wt, j, 64);
            int   sj = __shfl(sp, j, 64);
            float2 hv = ((const float2*)(h + (size_t)sj * HIDDEN))[l];
            acc.x += w * hv.x;
            acc.y += w * hv.y;
            wsum  += w;
        }
    }
    float selfc = sdv[LAYER] * (1.f / (float)N_EDGES);
    float lg = alpha[i] + beta_i + selfc;
    lg = lg > 0.f ? lg : NEG * lg;
    float exi = expf(lg);
    float denom = wsum + exi + 1e-16f;
    float2 hv = ((const float2*)(h + (size_t)i * HIDDEN))[l];
    float2 bb = ((const float2*)b)[l];
    float2 v;
    v.x = (acc.x + exi * hv.x) / denom + bb.x;
    v.y = (acc.y + exi * hv.y) / denom + bb.y;
    if (FINAL == 0) {
        ((float2*)(outp + (size_t)i * HIDDEN))[l] =
            make_float2(fmaxf(v.x, 0.f), fmaxf(v.y, 0.f));
    } else {
        float2 wl = ((const float2*)Wl)[l];
        float contrib = v.x * wl.x + v.y * wl.y;
        for (int off = 32; off > 0; off >>= 1) contrib += __shfl_down(contrib, off, 64);
        if (l == 0) outp[i] = fmaxf(contrib + bl[0], 0.f);
    }
}

// ---------------------------------------------------------------------------
extern "C" void kernel_launch(void* const* d_in, const int* in_sizes, int n_in,
                              void* d_out, int out_size, void* d_ws, size_t ws_size,
                              hipStream_t stream) {
    const float* x   = (const float*)d_in[0];
    const int*   src = (const int*)  d_in[1];
    const int*   dst = (const int*)  d_in[2];
    const float* ea  = (const float*)d_in[3];
    const float* W1  = (const float*)d_in[4];
    const float* We1 = (const float*)d_in[5];
    const float* as1 = (const float*)d_in[6];
    const float* ad1 = (const float*)d_in[7];
    const float* ae1 = (const float*)d_in[8];
    const float* b1  = (const float*)d_in[9];
    const float* W2  = (const float*)d_in[10];
    const float* We2 = (const float*)d_in[11];
    const float* as2 = (const float*)d_in[12];
    const float* ad2 = (const float*)d_in[13];
    const float* ae2 = (const float*)d_in[14];
    const float* b2  = (const float*)d_in[15];
    const float* Wl  = (const float*)d_in[16];
    const float* bl  = (const float*)d_in[17];
    float* out = (float*)d_out;

    float* ws      = (float*)d_ws;
    float* A       = ws;                           // [N*128]  h1, then h2
    float* B       = A + (size_t)N_NODES * HIDDEN; // [N*128]  out1 (conv1 result)
    float4* erec   = (float4*)(B + (size_t)N_NODES * HIDDEN);  // [E] packed (16B aligned)
    unsigned short* whp1 = (unsigned short*)(erec + N_EDGES);
    unsigned short* wlp1 = whp1 + 16384;
    unsigned short* whp2 = wlp1 + 16384;
    unsigned short* wlp2 = whp2 + 16384;
    float* alpha   = (float*)(wlp2 + 16384);       // [N]
    float* beta    = alpha + N_NODES;              // [N]
    float* consts  = beta + N_NODES;               // [64] ce1, ce2
    float* part    = consts + 64;                  // [64*16] padded partials
    float* sdv     = part + 64 * 16;               // [2]
    int* count     = (int*)(sdv + 2);              // [N]
    int* off_work  = count + N_NODES;              // [N]
    int* blocksum  = off_work + N_NODES;           // [SCAN_BLOCKS]
    int* blockoff  = blocksum + SCAN_BLOCKS;       // [SCAN_BLOCKS]

    const int EB = (N_EDGES + 255) / 256;
    const int EB2 = (N_EDGES + 511) / 512;

    // ---- prep: constants, W frag pack, CSR build fused with ea pass ----
    hipMemsetAsync(count, 0, N_NODES * sizeof(int), stream);
    hipMemsetAsync(part, 0, 64 * 16 * sizeof(float), stream);
    prep_kernel<<<1, 64, 0, stream>>>(We1, ae1, We2, ae2, consts);
    pack_w_kernel<<<64, 256, 0, stream>>>(W1, whp1, wlp1);
    pack_w_kernel<<<64, 256, 0, stream>>>(W2, whp2, wlp2);
    hist_kernel<<<EB, 256, 0, stream>>>(dst, count);
    scan1_kernel<<<SCAN_BLOCKS, 256, 0, stream>>>(count, off_work, blocksum);
    scan2_kernel<<<1, 256, 0, stream>>>(blocksum, blockoff);
    scan3_kernel<<<SCAN_BLOCKS, 256, 0, stream>>>(off_work, blockoff);
    scatter_dotv_kernel<<<EB2, 256, 0, stream>>>(src, dst, ea, consts, off_work,
                                                 erec, part);
    reduce_sdv_kernel<<<1, 64, 0, stream>>>(part, sdv);

    // ---- conv1 ----
    gemm_mfma_kernel<<<GEMM_BLOCKS, 256, 0, stream>>>(x, whp1, wlp1, as1, ad1,
                                                      A, alpha, beta);
    agg_kernel<0, 0><<<N_NODES / 4, 256, 0, stream>>>(off_work, erec, A, alpha, beta,
                                                      b1, sdv, nullptr, nullptr, B);

    // ---- conv2 (+ final linear fused) ----
    gemm_mfma_kernel<<<GEMM_BLOCKS, 256, 0, stream>>>(B, whp2, wlp2, as2, ad2,
                                                      A, alpha, beta);
    agg_kernel<1, 1><<<N_NODES / 4, 256, 0, stream>>>(off_work, erec, A, alpha, beta,
                                                      b2, sdv, Wl, bl, out);
}

// Round 13
// 262.194 us; speedup vs baseline: 2.1990x; 1.0197x over previous
//
#include <hip/hip_runtime.h>
#include <math.h>

#define N_NODES 50000
#define N_EDGES 800000
#define HIDDEN  128
#define EDIM    32
#define NEG     0.2f

typedef __attribute__((ext_vector_type(8))) short bshort8;
typedef __attribute__((ext_vector_type(4))) float f32x4;

__device__ __forceinline__ unsigned short f2bf(float f) {
    unsigned u = __builtin_bit_cast(unsigned, f);
    return (unsigned short)((u + 0x7FFFu + ((u >> 16) & 1u)) >> 16);
}
__device__ __forceinline__ float bf2f(unsigned short b) {
    unsigned u = ((unsigned)b) << 16;
    return __builtin_bit_cast(float, u);
}

// ---------------------------------------------------------------------------
// ce1 = We1 @ ae1, ce2 = We2 @ ae2 (each [32])
__global__ void prep_kernel(const float* __restrict__ We1, const float* __restrict__ ae1,
                            const float* __restrict__ We2, const float* __restrict__ ae2,
                            float* __restrict__ consts) {
    int t = threadIdx.x;
    if (t < 32) {
        float acc = 0.f;
        for (int k = 0; k < HIDDEN; k++) acc += We1[t * HIDDEN + k] * ae1[k];
        consts[t] = acc;
    } else if (t < 64) {
        int j = t - 32;
        float acc = 0.f;
        for (int k = 0; k < HIDDEN; k++) acc += We2[j * HIDDEN + k] * ae2[k];
        consts[32 + j] = acc;
    }
}

// ---------------------------------------------------------------------------
// Pack W (128x128 row-major, [k][col]) into MFMA B-fragment order, bf16 split.
__global__ void pack_w_kernel(const float* __restrict__ W,
                              unsigned short* __restrict__ whp,
                              unsigned short* __restrict__ wlp) {
    int idx = blockIdx.x * 256 + threadIdx.x;   // 16384 total
    int e  = idx & 7;
    int l  = (idx >> 3) & 63;
    int kc = (idx >> 9) & 3;
    int ct = (idx >> 11);
    int k   = kc * 32 + ((l >> 4) << 3) + e;
    int col = ct * 16 + (l & 15);
    float w = W[k * HIDDEN + col];
    unsigned short hb = f2bf(w);
    whp[idx] = hb;
    wlp[idx] = f2bf(w - bf2f(hb));
}

// ---------------------------------------------------------------------------
// CSR build step 1: in-degree histogram; atomic return value = edge rank
// within its destination segment (captured for the atomic-free scatter).
__global__ void hist_kernel(const int* __restrict__ dst, int* __restrict__ count,
                            int* __restrict__ rank) {
    int e = blockIdx.x * blockDim.x + threadIdx.x;
    if (e < N_EDGES) rank[e] = atomicAdd(&count[dst[e]], 1);
}

#define SCAN_BLOCKS ((N_NODES + 255) / 256)   // 196
__global__ void scan1_kernel(const int* __restrict__ count,
                             int* __restrict__ off_work, int* __restrict__ blocksum) {
    __shared__ int sh[256];
    int t = threadIdx.x;
    int idx = blockIdx.x * 256 + t;
    int v = (idx < N_NODES) ? count[idx] : 0;
    sh[t] = v;
    __syncthreads();
    for (int off = 1; off < 256; off <<= 1) {
        int u = (t >= off) ? sh[t - off] : 0;
        __syncthreads();
        sh[t] += u;
        __syncthreads();
    }
    if (idx < N_NODES) off_work[idx] = sh[t] - v;
    if (t == 255) blocksum[blockIdx.x] = sh[255];
}
__global__ void scan2_kernel(int* __restrict__ blocksum, int* __restrict__ blockoff) {
    __shared__ int sh[256];
    int t = threadIdx.x;
    int v = (t < SCAN_BLOCKS) ? blocksum[t] : 0;
    sh[t] = v;
    __syncthreads();
    for (int off = 1; off < 256; off <<= 1) {
        int u = (t >= off) ? sh[t - off] : 0;
        __syncthreads();
        sh[t] += u;
        __syncthreads();
    }
    if (t < SCAN_BLOCKS) blockoff[t] = sh[t] - v;
}
__global__ void scan3_kernel(int* __restrict__ off_work, const int* __restrict__ blockoff) {
    int idx = blockIdx.x * 256 + threadIdx.x;
    if (idx < N_NODES) off_work[idx] += blockoff[blockIdx.x];
}

// ---------------------------------------------------------------------------
// ATOMIC-FREE fused scatter + edge-scalar pass (one coalesced ea read):
//   pos = off_work[dst[e]] + rank[e]   (plain cached read, no atomic)
//   erec[pos] = {d1, d2, bitcast(src), 0}
// off_work stays an exclusive scan (agg segment = [off[i], off[i]+count[i])).
__global__ void scatter_dotv_kernel(const int* __restrict__ src, const int* __restrict__ dst,
                                    const int* __restrict__ rank,
                                    const float* __restrict__ ea,
                                    const float* __restrict__ consts,
                                    const int* __restrict__ off_work,
                                    float4* __restrict__ erec,
                                    float* __restrict__ part) {
    __shared__ float cs[64];
    int t = threadIdx.x;
    if (t < 64) cs[t] = consts[t];
    __syncthreads();
    int e = blockIdx.x * blockDim.x + t;   // N_EDGES % 256 == 0
    const float4* ep = (const float4*)(ea + (size_t)e * EDIM);
    float d1 = 0.f, d2 = 0.f;
#pragma unroll
    for (int i = 0; i < 8; i++) {
        float4 v = ep[i];
        d1 += v.x * cs[4 * i] + v.y * cs[4 * i + 1] + v.z * cs[4 * i + 2] + v.w * cs[4 * i + 3];
        d2 += v.x * cs[32 + 4 * i] + v.y * cs[32 + 4 * i + 1] + v.z * cs[32 + 4 * i + 2] + v.w * cs[32 + 4 * i + 3];
    }
    int pos = off_work[dst[e]] + rank[e];
    erec[pos] = make_float4(d1, d2, __int_as_float(src[e]), 0.f);
    float s1 = d1, s2 = d2;
    for (int off = 32; off > 0; off >>= 1) {
        s1 += __shfl_down(s1, off, 64);
        s2 += __shfl_down(s2, off, 64);
    }
    if ((t & 63) == 0) {
        int slot = (blockIdx.x & 63) * 16;
        atomicAdd(&part[slot], s1);
        atomicAdd(&part[slot + 1], s2);
    }
}

__global__ void reduce_sdv_kernel(const float* __restrict__ part, float* __restrict__ sdv) {
    int t = threadIdx.x;   // 64 threads
    float s1 = part[t * 16], s2 = part[t * 16 + 1];
    for (int off = 32; off > 0; off >>= 1) {
        s1 += __shfl_down(s1, off, 64);
        s2 += __shfl_down(s2, off, 64);
    }
    if (t == 0) { sdv[0] = s1; sdv[1] = s2; }
}

// ---------------------------------------------------------------------------
// MFMA gemm: h = x @ W via bf16 split (xh+xl)@(Wh+Wl), dropping xl@Wl.
// One wave per 16-row tile; 4 waves/block. h stored row-major [N][128].
#define TILES_M (N_NODES / 16)                // 3125
#define GEMM_BLOCKS ((TILES_M + 3) / 4)       // 782
__global__ void __launch_bounds__(256)
gemm_mfma_kernel(const float* __restrict__ x,
                 const unsigned short* __restrict__ wh,
                 const unsigned short* __restrict__ wl,
                 const float* __restrict__ a_s, const float* __restrict__ a_d,
                 float* __restrict__ h, float* __restrict__ alpha,
                 float* __restrict__ beta) {
    int tile = blockIdx.x * 4 + (threadIdx.x >> 6);
    if (tile >= TILES_M) return;
    int l    = threadIdx.x & 63;
    int row0 = tile * 16;
    int arow = l & 15;            // A row / D col
    int kg   = l >> 4;            // k-group / D row-group
    bshort8 ah[4], al[4];
    const float* xr = x + (size_t)(row0 + arow) * HIDDEN + (kg << 3);
#pragma unroll
    for (int kc = 0; kc < 4; kc++) {
        float4 f0 = *(const float4*)(xr + kc * 32);
        float4 f1 = *(const float4*)(xr + kc * 32 + 4);
        float fv[8] = {f0.x, f0.y, f0.z, f0.w, f1.x, f1.y, f1.z, f1.w};
#pragma unroll
        for (int e = 0; e < 8; e++) {
            unsigned short hb = f2bf(fv[e]);
            ah[kc][e] = (short)hb;
            al[kc][e] = (short)f2bf(fv[e] - bf2f(hb));
        }
    }
    float pal[4] = {0.f, 0.f, 0.f, 0.f};
    float pbe[4] = {0.f, 0.f, 0.f, 0.f};
#pragma unroll
    for (int ct = 0; ct < 8; ct++) {
        f32x4 acc = {0.f, 0.f, 0.f, 0.f};
#pragma unroll
        for (int kc = 0; kc < 4; kc++) {
            int fo = (((ct * 4 + kc) * 64) + l) << 3;
            bshort8 bh = *(const bshort8*)(wh + fo);
            bshort8 bl = *(const bshort8*)(wl + fo);
            acc = __builtin_amdgcn_mfma_f32_16x16x32_bf16(ah[kc], bh, acc, 0, 0, 0);
            acc = __builtin_amdgcn_mfma_f32_16x16x32_bf16(al[kc], bh, acc, 0, 0, 0);
            acc = __builtin_amdgcn_mfma_f32_16x16x32_bf16(ah[kc], bl, acc, 0, 0, 0);
        }
        int col = ct * 16 + arow;
        float a_sc = a_s[col], a_dc = a_d[col];
#pragma unroll
        for (int j = 0; j < 4; j++) {
            h[(size_t)(row0 + kg * 4 + j) * HIDDEN + col] = acc[j];
            pal[j] += acc[j] * a_sc;
            pbe[j] += acc[j] * a_dc;
        }
    }
#pragma unroll
    for (int m = 1; m < 16; m <<= 1) {
#pragma unroll
        for (int j = 0; j < 4; j++) {
            pal[j] += __shfl_xor(pal[j], m, 64);
            pbe[j] += __shfl_xor(pbe[j], m, 64);
        }
    }
    if (arow == 0) {
#pragma unroll
        for (int j = 0; j < 4; j++) {
            alpha[row0 + kg * 4 + j] = pal[j];
            beta[row0 + kg * 4 + j]  = pbe[j];
        }
    }
}

// ---------------------------------------------------------------------------
// Gather-aggregate: ONE WAVE PER NODE (4 nodes / 256-block, no barriers).
// Lane l owns channels 2l, 2l+1 (float2). Edge record = packed float4.
// Edge loop unrolled x8/x4 with batched gathers for memory-level parallelism.
template<int LAYER, int FINAL>
__global__ void __launch_bounds__(256)
agg_kernel(const int* __restrict__ off_work, const int* __restrict__ count,
           const float4* __restrict__ erec,
           const float* __restrict__ h,
           const float* __restrict__ alpha, const float* __restrict__ beta,
           const float* __restrict__ b, const float* __restrict__ sdv,
           const float* __restrict__ Wl, const float* __restrict__ bl,
           float* __restrict__ outp) {
    int t = threadIdx.x;
    int l = t & 63;
    int i = blockIdx.x * 4 + (t >> 6);
    int start = off_work[i];
    int end   = start + count[i];
    float beta_i = beta[i];
    float2 acc = make_float2(0.f, 0.f);
    float wsum = 0.f;
    for (int cb = start; cb < end; cb += 64) {
        int n = min(64, end - cb);
        int sp = 0; float wt = 0.f;
        if (l < n) {
            float4 rec = erec[cb + l];
            sp = __float_as_int(rec.z);
            float lg = alpha[sp] + beta_i + (LAYER == 0 ? rec.x : rec.y);
            lg = lg > 0.f ? lg : NEG * lg;
            wt = expf(lg);
        }
        int j = 0;
        for (; j + 8 <= n; j += 8) {
            float w8[8]; int s8[8]; float2 h8[8];
#pragma unroll
            for (int q = 0; q < 8; q++) {
                w8[q] = __shfl(wt, j + q, 64);
                s8[q] = __shfl(sp, j + q, 64);
            }
#pragma unroll
            for (int q = 0; q < 8; q++)
                h8[q] = ((const float2*)(h + (size_t)s8[q] * HIDDEN))[l];
#pragma unroll
            for (int q = 0; q < 8; q++) {
                acc.x += w8[q] * h8[q].x;
                acc.y += w8[q] * h8[q].y;
                wsum  += w8[q];
            }
        }
        for (; j + 4 <= n; j += 4) {
            float w4[4]; int s4[4]; float2 h4[4];
#pragma unroll
            for (int q = 0; q < 4; q++) {
                w4[q] = __shfl(wt, j + q, 64);
                s4[q] = __shfl(sp, j + q, 64);
            }
#pragma unroll
            for (int q = 0; q < 4; q++)
                h4[q] = ((const float2*)(h + (size_t)s4[q] * HIDDEN))[l];
#pragma unroll
            for (int q = 0; q < 4; q++) {
                acc.x += w4[q] * h4[q].x;
                acc.y += w4[q] * h4[q].y;
                wsum  += w4[q];
            }
        }
        for (; j < n; j++) {
            float w = __shfl(wt, j, 64);
            int   sj = __shfl(sp, j, 64);
            float2 hv = ((const float2*)(h + (size_t)sj * HIDDEN))[l];
            acc.x += w * hv.x;
            acc.y += w * hv.y;
            wsum  += w;
        }
    }
    float selfc = sdv[LAYER] * (1.f / (float)N_EDGES);
    float lg = alpha[i] + beta_i + selfc;
    lg = lg > 0.f ? lg : NEG * lg;
    float exi = expf(lg);
    float denom = wsum + exi + 1e-16f;
    float2 hv = ((const float2*)(h + (size_t)i * HIDDEN))[l];
    float2 bb = ((const float2*)b)[l];
    float2 v;
    v.x = (acc.x + exi * hv.x) / denom + bb.x;
    v.y = (acc.y + exi * hv.y) / denom + bb.y;
    if (FINAL == 0) {
        ((float2*)(outp + (size_t)i * HIDDEN))[l] =
            make_float2(fmaxf(v.x, 0.f), fmaxf(v.y, 0.f));
    } else {
        float2 wl = ((const float2*)Wl)[l];
        float contrib = v.x * wl.x + v.y * wl.y;
        for (int off = 32; off > 0; off >>= 1) contrib += __shfl_down(contrib, off, 64);
        if (l == 0) outp[i] = fmaxf(contrib + bl[0], 0.f);
    }
}

// ---------------------------------------------------------------------------
extern "C" void kernel_launch(void* const* d_in, const int* in_sizes, int n_in,
                              void* d_out, int out_size, void* d_ws, size_t ws_size,
                              hipStream_t stream) {
    const float* x   = (const float*)d_in[0];
    const int*   src = (const int*)  d_in[1];
    const int*   dst = (const int*)  d_in[2];
    const float* ea  = (const float*)d_in[3];
    const float* W1  = (const float*)d_in[4];
    const float* We1 = (const float*)d_in[5];
    const float* as1 = (const float*)d_in[6];
    const float* ad1 = (const float*)d_in[7];
    const float* ae1 = (const float*)d_in[8];
    const float* b1  = (const float*)d_in[9];
    const float* W2  = (const float*)d_in[10];
    const float* We2 = (const float*)d_in[11];
    const float* as2 = (const float*)d_in[12];
    const float* ad2 = (const float*)d_in[13];
    const float* ae2 = (const float*)d_in[14];
    const float* b2  = (const float*)d_in[15];
    const float* Wl  = (const float*)d_in[16];
    const float* bl  = (const float*)d_in[17];
    float* out = (float*)d_out;

    float* ws      = (float*)d_ws;
    float* A       = ws;                           // [N*128]  h1, then h2
    float* B       = A + (size_t)N_NODES * HIDDEN; // [N*128]  out1 (conv1 result)
    float4* erec   = (float4*)(B + (size_t)N_NODES * HIDDEN);  // [E] packed (16B aligned)
    unsigned short* whp1 = (unsigned short*)(erec + N_EDGES);
    unsigned short* wlp1 = whp1 + 16384;
    unsigned short* whp2 = wlp1 + 16384;
    unsigned short* wlp2 = whp2 + 16384;
    float* alpha   = (float*)(wlp2 + 16384);       // [N]
    float* beta    = alpha + N_NODES;              // [N]
    float* consts  = beta + N_NODES;               // [64] ce1, ce2
    float* part    = consts + 64;                  // [64*16] padded partials
    float* sdv     = part + 64 * 16;               // [2]
    int* count     = (int*)(sdv + 2);              // [N]
    int* off_work  = count + N_NODES;              // [N]
    int* blocksum  = off_work + N_NODES;           // [SCAN_BLOCKS]
    int* blockoff  = blocksum + SCAN_BLOCKS;       // [SCAN_BLOCKS]
    int* rank      = blockoff + SCAN_BLOCKS;       // [E] edge rank in segment

    const int EB = (N_EDGES + 255) / 256;

    // ---- prep: constants, W frag pack, CSR build fused with ea pass ----
    hipMemsetAsync(count, 0, N_NODES * sizeof(int), stream);
    hipMemsetAsync(part, 0, 64 * 16 * sizeof(float), stream);
    prep_kernel<<<1, 64, 0, stream>>>(We1, ae1, We2, ae2, consts);
    pack_w_kernel<<<64, 256, 0, stream>>>(W1, whp1, wlp1);
    pack_w_kernel<<<64, 256, 0, stream>>>(W2, whp2, wlp2);
    hist_kernel<<<EB, 256, 0, stream>>>(dst, count, rank);
    scan1_kernel<<<SCAN_BLOCKS, 256, 0, stream>>>(count, off_work, blocksum);
    scan2_kernel<<<1, 256, 0, stream>>>(blocksum, blockoff);
    scan3_kernel<<<SCAN_BLOCKS, 256, 0, stream>>>(off_work, blockoff);
    scatter_dotv_kernel<<<EB, 256, 0, stream>>>(src, dst, rank, ea, consts, off_work,
                                                erec, part);
    reduce_sdv_kernel<<<1, 64, 0, stream>>>(part, sdv);

    // ---- conv1 ----
    gemm_mfma_kernel<<<GEMM_BLOCKS, 256, 0, stream>>>(x, whp1, wlp1, as1, ad1,
                                                      A, alpha, beta);
    agg_kernel<0, 0><<<N_NODES / 4, 256, 0, stream>>>(off_work, count, erec, A, alpha, beta,
                                                      b1, sdv, nullptr, nullptr, B);

    // ---- conv2 (+ final linear fused) ----
    gemm_mfma_kernel<<<GEMM_BLOCKS, 256, 0, stream>>>(B, whp2, wlp2, as2, ad2,
                                                      A, alpha, beta);
    agg_kernel<1, 1><<<N_NODES / 4, 256, 0, stream>>>(off_work, count, erec, A, alpha, beta,
                                                      b2, sdv, Wl, bl, out);
}

// Round 14
// 253.240 us; speedup vs baseline: 2.2768x; 1.0354x over previous
//
#include <hip/hip_runtime.h>
#include <math.h>

#define N_NODES 50000
#define N_EDGES 800000
#define HIDDEN  128
#define EDIM    32
#define NEG     0.2f

typedef __attribute__((ext_vector_type(8))) short bshort8;
typedef __attribute__((ext_vector_type(4))) float f32x4;

__device__ __forceinline__ unsigned short f2bf(float f) {
    unsigned u = __builtin_bit_cast(unsigned, f);
    return (unsigned short)((u + 0x7FFFu + ((u >> 16) & 1u)) >> 16);
}
__device__ __forceinline__ float bf2f(unsigned short b) {
    unsigned u = ((unsigned)b) << 16;
    return __builtin_bit_cast(float, u);
}

#define TILES_M (N_NODES / 16)                // 3125
#define GEMM_BLOCKS ((TILES_M + 3) / 4)       // 782
#define EB (N_EDGES / 256)                    // 3125
#define SCAN_BLOCKS ((N_NODES + 255) / 256)   // 196

// ---------------------------------------------------------------------------
// device bodies
// ---------------------------------------------------------------------------
__device__ __forceinline__ void pack_w_body(int idx, const float* __restrict__ W,
                                            unsigned short* __restrict__ whp,
                                            unsigned short* __restrict__ wlp) {
    int e  = idx & 7;
    int l  = (idx >> 3) & 63;
    int kc = (idx >> 9) & 3;
    int ct = (idx >> 11);
    int k   = kc * 32 + ((l >> 4) << 3) + e;
    int col = ct * 16 + (l & 15);
    float w = W[k * HIDDEN + col];
    unsigned short hb = f2bf(w);
    whp[idx] = hb;
    wlp[idx] = f2bf(w - bf2f(hb));
}

// MFMA gemm tile: h = x @ W via bf16 split (xh+xl)@(Wh+Wl), dropping xl@Wl.
// One wave per 16-row tile. fused alpha/beta dots.
__device__ __forceinline__ void gemm_body(int tile, int t,
                                          const float* __restrict__ x,
                                          const unsigned short* __restrict__ wh,
                                          const unsigned short* __restrict__ wl,
                                          const float* __restrict__ a_s,
                                          const float* __restrict__ a_d,
                                          float* __restrict__ h,
                                          float* __restrict__ alpha,
                                          float* __restrict__ beta) {
    int l    = t & 63;
    int row0 = tile * 16;
    int arow = l & 15;            // A row / D col
    int kg   = l >> 4;            // k-group / D row-group
    bshort8 ah[4], al[4];
    const float* xr = x + (size_t)(row0 + arow) * HIDDEN + (kg << 3);
#pragma unroll
    for (int kc = 0; kc < 4; kc++) {
        float4 f0 = *(const float4*)(xr + kc * 32);
        float4 f1 = *(const float4*)(xr + kc * 32 + 4);
        float fv[8] = {f0.x, f0.y, f0.z, f0.w, f1.x, f1.y, f1.z, f1.w};
#pragma unroll
        for (int e = 0; e < 8; e++) {
            unsigned short hb = f2bf(fv[e]);
            ah[kc][e] = (short)hb;
            al[kc][e] = (short)f2bf(fv[e] - bf2f(hb));
        }
    }
    float pal[4] = {0.f, 0.f, 0.f, 0.f};
    float pbe[4] = {0.f, 0.f, 0.f, 0.f};
#pragma unroll
    for (int ct = 0; ct < 8; ct++) {
        f32x4 acc = {0.f, 0.f, 0.f, 0.f};
#pragma unroll
        for (int kc = 0; kc < 4; kc++) {
            int fo = (((ct * 4 + kc) * 64) + l) << 3;
            bshort8 bh = *(const bshort8*)(wh + fo);
            bshort8 bl = *(const bshort8*)(wl + fo);
            acc = __builtin_amdgcn_mfma_f32_16x16x32_bf16(ah[kc], bh, acc, 0, 0, 0);
            acc = __builtin_amdgcn_mfma_f32_16x16x32_bf16(al[kc], bh, acc, 0, 0, 0);
            acc = __builtin_amdgcn_mfma_f32_16x16x32_bf16(ah[kc], bl, acc, 0, 0, 0);
        }
        int col = ct * 16 + arow;
        float a_sc = a_s[col], a_dc = a_d[col];
#pragma unroll
        for (int j = 0; j < 4; j++) {
            h[(size_t)(row0 + kg * 4 + j) * HIDDEN + col] = acc[j];
            pal[j] += acc[j] * a_sc;
            pbe[j] += acc[j] * a_dc;
        }
    }
#pragma unroll
    for (int m = 1; m < 16; m <<= 1) {
#pragma unroll
        for (int j = 0; j < 4; j++) {
            pal[j] += __shfl_xor(pal[j], m, 64);
            pbe[j] += __shfl_xor(pbe[j], m, 64);
        }
    }
    if (arow == 0) {
#pragma unroll
        for (int j = 0; j < 4; j++) {
            alpha[row0 + kg * 4 + j] = pal[j];
            beta[row0 + kg * 4 + j]  = pbe[j];
        }
    }
}

// ---------------------------------------------------------------------------
// FUSED prep: hist (EB blocks) | pack W1 (64) | pack W2 (64) | prep consts (1)
__global__ void __launch_bounds__(256)
fused_prep_kernel(const int* __restrict__ dst, int* __restrict__ count,
                  int* __restrict__ rank,
                  const float* __restrict__ W1, unsigned short* __restrict__ whp1,
                  unsigned short* __restrict__ wlp1,
                  const float* __restrict__ W2, unsigned short* __restrict__ whp2,
                  unsigned short* __restrict__ wlp2,
                  const float* __restrict__ We1, const float* __restrict__ ae1,
                  const float* __restrict__ We2, const float* __restrict__ ae2,
                  float* __restrict__ consts) {
    int b = blockIdx.x, t = threadIdx.x;
    if (b < EB) {
        int e = b * 256 + t;
        rank[e] = atomicAdd(&count[dst[e]], 1);
    } else if (b < EB + 64) {
        pack_w_body((b - EB) * 256 + t, W1, whp1, wlp1);
    } else if (b < EB + 128) {
        pack_w_body((b - EB - 64) * 256 + t, W2, whp2, wlp2);
    } else {
        if (t < 32) {
            float acc = 0.f;
            for (int k = 0; k < HIDDEN; k++) acc += We1[t * HIDDEN + k] * ae1[k];
            consts[t] = acc;
        } else if (t < 64) {
            int j = t - 32;
            float acc = 0.f;
            for (int k = 0; k < HIDDEN; k++) acc += We2[j * HIDDEN + k] * ae2[k];
            consts[32 + j] = acc;
        }
    }
}

// ---------------------------------------------------------------------------
// 3-phase scan
__global__ void scan1_kernel(const int* __restrict__ count,
                             int* __restrict__ off_work, int* __restrict__ blocksum) {
    __shared__ int sh[256];
    int t = threadIdx.x;
    int idx = blockIdx.x * 256 + t;
    int v = (idx < N_NODES) ? count[idx] : 0;
    sh[t] = v;
    __syncthreads();
    for (int off = 1; off < 256; off <<= 1) {
        int u = (t >= off) ? sh[t - off] : 0;
        __syncthreads();
        sh[t] += u;
        __syncthreads();
    }
    if (idx < N_NODES) off_work[idx] = sh[t] - v;
    if (t == 255) blocksum[blockIdx.x] = sh[255];
}
__global__ void scan2_kernel(int* __restrict__ blocksum, int* __restrict__ blockoff) {
    __shared__ int sh[256];
    int t = threadIdx.x;
    int v = (t < SCAN_BLOCKS) ? blocksum[t] : 0;
    sh[t] = v;
    __syncthreads();
    for (int off = 1; off < 256; off <<= 1) {
        int u = (t >= off) ? sh[t - off] : 0;
        __syncthreads();
        sh[t] += u;
        __syncthreads();
    }
    if (t < SCAN_BLOCKS) blockoff[t] = sh[t] - v;
}
__global__ void scan3_kernel(int* __restrict__ off_work, const int* __restrict__ blockoff) {
    int idx = blockIdx.x * 256 + threadIdx.x;
    if (idx < N_NODES) off_work[idx] += blockoff[blockIdx.x];
}

// ---------------------------------------------------------------------------
// FUSED scatter_dotv + gemm(layer1): independent stages co-resident on CUs.
// Block role: (b&3)==3 && (b>>2)<GEMM_BLOCKS -> gemm tile-group b>>2;
// else scatter group sid = b - min((b+1)>>2, GEMM_BLOCKS).  3:1 interleave.
__global__ void __launch_bounds__(256)
fused_scatter_gemm_kernel(const int* __restrict__ src, const int* __restrict__ dst,
                          const int* __restrict__ rank,
                          const float* __restrict__ ea,
                          const float* __restrict__ consts,
                          const int* __restrict__ off_work,
                          float4* __restrict__ erec, float* __restrict__ part,
                          const float* __restrict__ x,
                          const unsigned short* __restrict__ wh,
                          const unsigned short* __restrict__ wl,
                          const float* __restrict__ a_s, const float* __restrict__ a_d,
                          float* __restrict__ h, float* __restrict__ alpha,
                          float* __restrict__ beta) {
    __shared__ float cs[64];
    int b = blockIdx.x, t = threadIdx.x;
    bool is_gemm = ((b & 3) == 3) && ((b >> 2) < GEMM_BLOCKS);
    if (is_gemm) {
        int tile = (b >> 2) * 4 + (t >> 6);
        if (tile < TILES_M)
            gemm_body(tile, t, x, wh, wl, a_s, a_d, h, alpha, beta);
        return;
    }
    int sid = b - min((b + 1) >> 2, GEMM_BLOCKS);
    if (t < 64) cs[t] = consts[t];
    __syncthreads();
    int e = sid * 256 + t;
    const float4* ep = (const float4*)(ea + (size_t)e * EDIM);
    float d1 = 0.f, d2 = 0.f;
#pragma unroll
    for (int i = 0; i < 8; i++) {
        float4 v = ep[i];
        d1 += v.x * cs[4 * i] + v.y * cs[4 * i + 1] + v.z * cs[4 * i + 2] + v.w * cs[4 * i + 3];
        d2 += v.x * cs[32 + 4 * i] + v.y * cs[32 + 4 * i + 1] + v.z * cs[32 + 4 * i + 2] + v.w * cs[32 + 4 * i + 3];
    }
    int pos = off_work[dst[e]] + rank[e];
    erec[pos] = make_float4(d1, d2, __int_as_float(src[e]), 0.f);
    float s1 = d1, s2 = d2;
    for (int off = 32; off > 0; off >>= 1) {
        s1 += __shfl_down(s1, off, 64);
        s2 += __shfl_down(s2, off, 64);
    }
    if ((t & 63) == 0) {
        int slot = (sid & 63) * 16;
        atomicAdd(&part[slot], s1);
        atomicAdd(&part[slot + 1], s2);
    }
}

// standalone gemm (layer 2)
__global__ void __launch_bounds__(256)
gemm_mfma_kernel(const float* __restrict__ x,
                 const unsigned short* __restrict__ wh,
                 const unsigned short* __restrict__ wl,
                 const float* __restrict__ a_s, const float* __restrict__ a_d,
                 float* __restrict__ h, float* __restrict__ alpha,
                 float* __restrict__ beta) {
    int tile = blockIdx.x * 4 + (threadIdx.x >> 6);
    if (tile >= TILES_M) return;
    gemm_body(tile, threadIdx.x, x, wh, wl, a_s, a_d, h, alpha, beta);
}

// ---------------------------------------------------------------------------
// Gather-aggregate: ONE WAVE PER NODE (4 nodes / 256-block, no barriers).
// Lane l owns channels 2l, 2l+1 (float2). Edge record = packed float4.
// selfc computed per-wave by reducing the 64 padded partial slots.
template<int LAYER, int FINAL>
__global__ void __launch_bounds__(256)
agg_kernel(const int* __restrict__ off_work, const int* __restrict__ count,
           const float4* __restrict__ erec,
           const float* __restrict__ h,
           const float* __restrict__ alpha, const float* __restrict__ beta,
           const float* __restrict__ b, const float* __restrict__ part,
           const float* __restrict__ Wl, const float* __restrict__ bl,
           float* __restrict__ outp) {
    int t = threadIdx.x;
    int l = t & 63;
    int i = blockIdx.x * 4 + (t >> 6);
    // per-wave reduction of sdv partials (replaces reduce_sdv dispatch)
    float ps = part[l * 16 + LAYER];
#pragma unroll
    for (int m = 32; m > 0; m >>= 1) ps += __shfl_xor(ps, m, 64);
    float selfc = ps * (1.f / (float)N_EDGES);
    int start = off_work[i];
    int end   = start + count[i];
    float beta_i = beta[i];
    float2 acc = make_float2(0.f, 0.f);
    float wsum = 0.f;
    for (int cb = start; cb < end; cb += 64) {
        int n = min(64, end - cb);
        int sp = 0; float wt = 0.f;
        if (l < n) {
            float4 rec = erec[cb + l];
            sp = __float_as_int(rec.z);
            float lg = alpha[sp] + beta_i + (LAYER == 0 ? rec.x : rec.y);
            lg = lg > 0.f ? lg : NEG * lg;
            wt = expf(lg);
        }
        int j = 0;
        for (; j + 8 <= n; j += 8) {
            float w8[8]; int s8[8]; float2 h8[8];
#pragma unroll
            for (int q = 0; q < 8; q++) {
                w8[q] = __shfl(wt, j + q, 64);
                s8[q] = __shfl(sp, j + q, 64);
            }
#pragma unroll
            for (int q = 0; q < 8; q++)
                h8[q] = ((const float2*)(h + (size_t)s8[q] * HIDDEN))[l];
#pragma unroll
            for (int q = 0; q < 8; q++) {
                acc.x += w8[q] * h8[q].x;
                acc.y += w8[q] * h8[q].y;
                wsum  += w8[q];
            }
        }
        for (; j + 4 <= n; j += 4) {
            float w4[4]; int s4[4]; float2 h4[4];
#pragma unroll
            for (int q = 0; q < 4; q++) {
                w4[q] = __shfl(wt, j + q, 64);
                s4[q] = __shfl(sp, j + q, 64);
            }
#pragma unroll
            for (int q = 0; q < 4; q++)
                h4[q] = ((const float2*)(h + (size_t)s4[q] * HIDDEN))[l];
#pragma unroll
            for (int q = 0; q < 4; q++) {
                acc.x += w4[q] * h4[q].x;
                acc.y += w4[q] * h4[q].y;
                wsum  += w4[q];
            }
        }
        for (; j < n; j++) {
            float w = __shfl(wt, j, 64);
            int   sj = __shfl(sp, j, 64);
            float2 hv = ((const float2*)(h + (size_t)sj * HIDDEN))[l];
            acc.x += w * hv.x;
            acc.y += w * hv.y;
            wsum  += w;
        }
    }
    float lg = alpha[i] + beta_i + selfc;
    lg = lg > 0.f ? lg : NEG * lg;
    float exi = expf(lg);
    float denom = wsum + exi + 1e-16f;
    float2 hv = ((const float2*)(h + (size_t)i * HIDDEN))[l];
    float2 bb = ((const float2*)b)[l];
    float2 v;
    v.x = (acc.x + exi * hv.x) / denom + bb.x;
    v.y = (acc.y + exi * hv.y) / denom + bb.y;
    if (FINAL == 0) {
        ((float2*)(outp + (size_t)i * HIDDEN))[l] =
            make_float2(fmaxf(v.x, 0.f), fmaxf(v.y, 0.f));
    } else {
        float2 wl = ((const float2*)Wl)[l];
        float contrib = v.x * wl.x + v.y * wl.y;
        for (int off = 32; off > 0; off >>= 1) contrib += __shfl_down(contrib, off, 64);
        if (l == 0) outp[i] = fmaxf(contrib + bl[0], 0.f);
    }
}

// ---------------------------------------------------------------------------
extern "C" void kernel_launch(void* const* d_in, const int* in_sizes, int n_in,
                              void* d_out, int out_size, void* d_ws, size_t ws_size,
                              hipStream_t stream) {
    const float* x   = (const float*)d_in[0];
    const int*   src = (const int*)  d_in[1];
    const int*   dst = (const int*)  d_in[2];
    const float* ea  = (const float*)d_in[3];
    const float* W1  = (const float*)d_in[4];
    const float* We1 = (const float*)d_in[5];
    const float* as1 = (const float*)d_in[6];
    const float* ad1 = (const float*)d_in[7];
    const float* ae1 = (const float*)d_in[8];
    const float* b1  = (const float*)d_in[9];
    const float* W2  = (const float*)d_in[10];
    const float* We2 = (const float*)d_in[11];
    const float* as2 = (const float*)d_in[12];
    const float* ad2 = (const float*)d_in[13];
    const float* ae2 = (const float*)d_in[14];
    const float* b2  = (const float*)d_in[15];
    const float* Wl  = (const float*)d_in[16];
    const float* bl  = (const float*)d_in[17];
    float* out = (float*)d_out;

    float* ws      = (float*)d_ws;
    float* A       = ws;                           // [N*128]  h1, then h2
    float* B       = A + (size_t)N_NODES * HIDDEN; // [N*128]  out1 (conv1 result)
    float4* erec   = (float4*)(B + (size_t)N_NODES * HIDDEN);  // [E] packed
    unsigned short* whp1 = (unsigned short*)(erec + N_EDGES);
    unsigned short* wlp1 = whp1 + 16384;
    unsigned short* whp2 = wlp1 + 16384;
    unsigned short* wlp2 = whp2 + 16384;
    float* alpha   = (float*)(wlp2 + 16384);       // [N]
    float* beta    = alpha + N_NODES;              // [N]
    float* consts  = beta + N_NODES;               // [64] ce1, ce2
    float* part    = consts + 64;                  // [64*16] padded partials
    float* sdv     = part + 64 * 16;               // [2] (unused, layout keep)
    int* count     = (int*)(sdv + 2);              // [N]
    int* off_work  = count + N_NODES;              // [N]
    int* blocksum  = off_work + N_NODES;           // [SCAN_BLOCKS]
    int* blockoff  = blocksum + SCAN_BLOCKS;       // [SCAN_BLOCKS]
    int* rank      = blockoff + SCAN_BLOCKS;       // [E] edge rank in segment

    // ---- prep (fused): hist + pack W1/W2 + consts ----
    hipMemsetAsync(count, 0, N_NODES * sizeof(int), stream);
    hipMemsetAsync(part, 0, 64 * 16 * sizeof(float), stream);
    fused_prep_kernel<<<EB + 129, 256, 0, stream>>>(dst, count, rank,
                                                    W1, whp1, wlp1, W2, whp2, wlp2,
                                                    We1, ae1, We2, ae2, consts);
    scan1_kernel<<<SCAN_BLOCKS, 256, 0, stream>>>(count, off_work, blocksum);
    scan2_kernel<<<1, 256, 0, stream>>>(blocksum, blockoff);
    scan3_kernel<<<SCAN_BLOCKS, 256, 0, stream>>>(off_work, blockoff);

    // ---- fused scatter (edge records) + gemm layer 1 ----
    fused_scatter_gemm_kernel<<<EB + GEMM_BLOCKS, 256, 0, stream>>>(
        src, dst, rank, ea, consts, off_work, erec, part,
        x, whp1, wlp1, as1, ad1, A, alpha, beta);

    // ---- conv1 aggregate ----
    agg_kernel<0, 0><<<N_NODES / 4, 256, 0, stream>>>(off_work, count, erec, A, alpha, beta,
                                                      b1, part, nullptr, nullptr, B);

    // ---- conv2 (+ final linear fused) ----
    gemm_mfma_kernel<<<GEMM_BLOCKS, 256, 0, stream>>>(B, whp2, wlp2, as2, ad2,
                                                      A, alpha, beta);
    agg_kernel<1, 1><<<N_NODES / 4, 256, 0, stream>>>(off_work, count, erec, A, alpha, beta,
                                                      b2, part, Wl, bl, out);
}

// Round 15
// 249.095 us; speedup vs baseline: 2.3147x; 1.0166x over previous
//
#include <hip/hip_runtime.h>
#include <math.h>

#define N_NODES 50000
#define N_EDGES 800000
#define HIDDEN  128
#define EDIM    32
#define NEG     0.2f

typedef __attribute__((ext_vector_type(8))) short bshort8;
typedef __attribute__((ext_vector_type(4))) float f32x4;

__device__ __forceinline__ unsigned short f2bf(float f) {
    unsigned u = __builtin_bit_cast(unsigned, f);
    return (unsigned short)((u + 0x7FFFu + ((u >> 16) & 1u)) >> 16);
}
__device__ __forceinline__ float bf2f(unsigned short b) {
    unsigned u = ((unsigned)b) << 16;
    return __builtin_bit_cast(float, u);
}

#define TILES_M (N_NODES / 16)                // 3125
#define GEMM_BLOCKS ((TILES_M + 3) / 4)       // 782
#define EB (N_EDGES / 256)                    // 3125
#define SCAN_BLOCKS ((N_NODES + 255) / 256)   // 196

// pipeline split: K1 = agg1 [0,X); K2 = agg1 [X,N) || gemm2 tiles [0,X/16)
#define X_SPLIT 35008
#define TILES_SPLIT (X_SPLIT / 16)            // 2188
#define AGG_B1 (X_SPLIT / 4)                  // 8752
#define AGG_B2 ((N_NODES - X_SPLIT) / 4)      // 3748
#define GEMM_B2 ((TILES_SPLIT + 3) / 4)       // 547
#define GEMM_B3 ((TILES_M - TILES_SPLIT + 3) / 4)  // 235

// ---------------------------------------------------------------------------
__device__ __forceinline__ void pack_w_body(int idx, const float* __restrict__ W,
                                            unsigned short* __restrict__ whp,
                                            unsigned short* __restrict__ wlp) {
    int e  = idx & 7;
    int l  = (idx >> 3) & 63;
    int kc = (idx >> 9) & 3;
    int ct = (idx >> 11);
    int k   = kc * 32 + ((l >> 4) << 3) + e;
    int col = ct * 16 + (l & 15);
    float w = W[k * HIDDEN + col];
    unsigned short hb = f2bf(w);
    whp[idx] = hb;
    wlp[idx] = f2bf(w - bf2f(hb));
}

// MFMA gemm tile: h = x @ W via bf16 split; one wave per 16-row tile.
__device__ __forceinline__ void gemm_body(int tile, int t,
                                          const float* __restrict__ x,
                                          const unsigned short* __restrict__ wh,
                                          const unsigned short* __restrict__ wl,
                                          const float* __restrict__ a_s,
                                          const float* __restrict__ a_d,
                                          float* __restrict__ h,
                                          float* __restrict__ alpha,
                                          float* __restrict__ beta) {
    int l    = t & 63;
    int row0 = tile * 16;
    int arow = l & 15;
    int kg   = l >> 4;
    bshort8 ah[4], al[4];
    const float* xr = x + (size_t)(row0 + arow) * HIDDEN + (kg << 3);
#pragma unroll
    for (int kc = 0; kc < 4; kc++) {
        float4 f0 = *(const float4*)(xr + kc * 32);
        float4 f1 = *(const float4*)(xr + kc * 32 + 4);
        float fv[8] = {f0.x, f0.y, f0.z, f0.w, f1.x, f1.y, f1.z, f1.w};
#pragma unroll
        for (int e = 0; e < 8; e++) {
            unsigned short hb = f2bf(fv[e]);
            ah[kc][e] = (short)hb;
            al[kc][e] = (short)f2bf(fv[e] - bf2f(hb));
        }
    }
    float pal[4] = {0.f, 0.f, 0.f, 0.f};
    float pbe[4] = {0.f, 0.f, 0.f, 0.f};
#pragma unroll
    for (int ct = 0; ct < 8; ct++) {
        f32x4 acc = {0.f, 0.f, 0.f, 0.f};
#pragma unroll
        for (int kc = 0; kc < 4; kc++) {
            int fo = (((ct * 4 + kc) * 64) + l) << 3;
            bshort8 bh = *(const bshort8*)(wh + fo);
            bshort8 bl = *(const bshort8*)(wl + fo);
            acc = __builtin_amdgcn_mfma_f32_16x16x32_bf16(ah[kc], bh, acc, 0, 0, 0);
            acc = __builtin_amdgcn_mfma_f32_16x16x32_bf16(al[kc], bh, acc, 0, 0, 0);
            acc = __builtin_amdgcn_mfma_f32_16x16x32_bf16(ah[kc], bl, acc, 0, 0, 0);
        }
        int col = ct * 16 + arow;
        float a_sc = a_s[col], a_dc = a_d[col];
#pragma unroll
        for (int j = 0; j < 4; j++) {
            h[(size_t)(row0 + kg * 4 + j) * HIDDEN + col] = acc[j];
            pal[j] += acc[j] * a_sc;
            pbe[j] += acc[j] * a_dc;
        }
    }
#pragma unroll
    for (int m = 1; m < 16; m <<= 1) {
#pragma unroll
        for (int j = 0; j < 4; j++) {
            pal[j] += __shfl_xor(pal[j], m, 64);
            pbe[j] += __shfl_xor(pbe[j], m, 64);
        }
    }
    if (arow == 0) {
#pragma unroll
        for (int j = 0; j < 4; j++) {
            alpha[row0 + kg * 4 + j] = pal[j];
            beta[row0 + kg * 4 + j]  = pbe[j];
        }
    }
}

// Gather-aggregate body: one wave per node i; lane l owns channels 2l,2l+1.
template<int LAYER, int FINAL>
__device__ __forceinline__ void agg_body(int i, int t,
                                         const int* __restrict__ off_work,
                                         const int* __restrict__ blockoff,
                                         const int* __restrict__ count,
                                         const float4* __restrict__ erec,
                                         const float* __restrict__ h,
                                         const float* __restrict__ alpha,
                                         const float* __restrict__ beta,
                                         const float* __restrict__ b,
                                         const float* __restrict__ part,
                                         const float* __restrict__ Wl,
                                         const float* __restrict__ bl,
                                         float* __restrict__ outp) {
    int l = t & 63;
    float ps = part[l * 16 + LAYER];
#pragma unroll
    for (int m = 32; m > 0; m >>= 1) ps += __shfl_xor(ps, m, 64);
    float selfc = ps * (1.f / (float)N_EDGES);
    int start = off_work[i] + blockoff[i >> 8];
    int end   = start + count[i];
    float beta_i = beta[i];
    float2 acc = make_float2(0.f, 0.f);
    float wsum = 0.f;
    for (int cb = start; cb < end; cb += 64) {
        int n = min(64, end - cb);
        int sp = 0; float wt = 0.f;
        if (l < n) {
            float4 rec = erec[cb + l];
            sp = __float_as_int(rec.z);
            float lg = alpha[sp] + beta_i + (LAYER == 0 ? rec.x : rec.y);
            lg = lg > 0.f ? lg : NEG * lg;
            wt = expf(lg);
        }
        int j = 0;
        for (; j + 8 <= n; j += 8) {
            float w8[8]; int s8[8]; float2 h8[8];
#pragma unroll
            for (int q = 0; q < 8; q++) {
                w8[q] = __shfl(wt, j + q, 64);
                s8[q] = __shfl(sp, j + q, 64);
            }
#pragma unroll
            for (int q = 0; q < 8; q++)
                h8[q] = ((const float2*)(h + (size_t)s8[q] * HIDDEN))[l];
#pragma unroll
            for (int q = 0; q < 8; q++) {
                acc.x += w8[q] * h8[q].x;
                acc.y += w8[q] * h8[q].y;
                wsum  += w8[q];
            }
        }
        for (; j + 4 <= n; j += 4) {
            float w4[4]; int s4[4]; float2 h4[4];
#pragma unroll
            for (int q = 0; q < 4; q++) {
                w4[q] = __shfl(wt, j + q, 64);
                s4[q] = __shfl(sp, j + q, 64);
            }
#pragma unroll
            for (int q = 0; q < 4; q++)
                h4[q] = ((const float2*)(h + (size_t)s4[q] * HIDDEN))[l];
#pragma unroll
            for (int q = 0; q < 4; q++) {
                acc.x += w4[q] * h4[q].x;
                acc.y += w4[q] * h4[q].y;
                wsum  += w4[q];
            }
        }
        for (; j < n; j++) {
            float w = __shfl(wt, j, 64);
            int   sj = __shfl(sp, j, 64);
            float2 hv = ((const float2*)(h + (size_t)sj * HIDDEN))[l];
            acc.x += w * hv.x;
            acc.y += w * hv.y;
            wsum  += w;
        }
    }
    float lg = alpha[i] + beta_i + selfc;
    lg = lg > 0.f ? lg : NEG * lg;
    float exi = expf(lg);
    float denom = wsum + exi + 1e-16f;
    float2 hv = ((const float2*)(h + (size_t)i * HIDDEN))[l];
    float2 bb = ((const float2*)b)[l];
    float2 v;
    v.x = (acc.x + exi * hv.x) / denom + bb.x;
    v.y = (acc.y + exi * hv.y) / denom + bb.y;
    if (FINAL == 0) {
        ((float2*)(outp + (size_t)i * HIDDEN))[l] =
            make_float2(fmaxf(v.x, 0.f), fmaxf(v.y, 0.f));
    } else {
        float2 wl = ((const float2*)Wl)[l];
        float contrib = v.x * wl.x + v.y * wl.y;
        for (int off = 32; off > 0; off >>= 1) contrib += __shfl_down(contrib, off, 64);
        if (l == 0) outp[i] = fmaxf(contrib + bl[0], 0.f);
    }
}

// ---------------------------------------------------------------------------
// FUSED prep: hist (EB blocks) | pack W1 (64) | pack W2 (64) | consts (1)
__global__ void __launch_bounds__(256)
fused_prep_kernel(const int* __restrict__ dst, int* __restrict__ count,
                  int* __restrict__ rank,
                  const float* __restrict__ W1, unsigned short* __restrict__ whp1,
                  unsigned short* __restrict__ wlp1,
                  const float* __restrict__ W2, unsigned short* __restrict__ whp2,
                  unsigned short* __restrict__ wlp2,
                  const float* __restrict__ We1, const float* __restrict__ ae1,
                  const float* __restrict__ We2, const float* __restrict__ ae2,
                  float* __restrict__ consts) {
    int b = blockIdx.x, t = threadIdx.x;
    if (b < EB) {
        int e = b * 256 + t;
        rank[e] = atomicAdd(&count[dst[e]], 1);
    } else if (b < EB + 64) {
        pack_w_body((b - EB) * 256 + t, W1, whp1, wlp1);
    } else if (b < EB + 128) {
        pack_w_body((b - EB - 64) * 256 + t, W2, whp2, wlp2);
    } else {
        if (t < 32) {
            float acc = 0.f;
            for (int k = 0; k < HIDDEN; k++) acc += We1[t * HIDDEN + k] * ae1[k];
            consts[t] = acc;
        } else if (t < 64) {
            int j = t - 32;
            float acc = 0.f;
            for (int k = 0; k < HIDDEN; k++) acc += We2[j * HIDDEN + k] * ae2[k];
            consts[32 + j] = acc;
        }
    }
}

// ---------------------------------------------------------------------------
// 2-phase scan (blockoff folded into consumers)
__global__ void scan1_kernel(const int* __restrict__ count,
                             int* __restrict__ off_work, int* __restrict__ blocksum) {
    __shared__ int sh[256];
    int t = threadIdx.x;
    int idx = blockIdx.x * 256 + t;
    int v = (idx < N_NODES) ? count[idx] : 0;
    sh[t] = v;
    __syncthreads();
    for (int off = 1; off < 256; off <<= 1) {
        int u = (t >= off) ? sh[t - off] : 0;
        __syncthreads();
        sh[t] += u;
        __syncthreads();
    }
    if (idx < N_NODES) off_work[idx] = sh[t] - v;
    if (t == 255) blocksum[blockIdx.x] = sh[255];
}
__global__ void scan2_kernel(int* __restrict__ blocksum, int* __restrict__ blockoff) {
    __shared__ int sh[256];
    int t = threadIdx.x;
    int v = (t < SCAN_BLOCKS) ? blocksum[t] : 0;
    sh[t] = v;
    __syncthreads();
    for (int off = 1; off < 256; off <<= 1) {
        int u = (t >= off) ? sh[t - off] : 0;
        __syncthreads();
        sh[t] += u;
        __syncthreads();
    }
    if (t < SCAN_BLOCKS) blockoff[t] = sh[t] - v;
}

// ---------------------------------------------------------------------------
// FUSED scatter_dotv + gemm(layer1), 4:1 block-role interleave.
__global__ void __launch_bounds__(256)
fused_scatter_gemm_kernel(const int* __restrict__ src, const int* __restrict__ dst,
                          const int* __restrict__ rank,
                          const float* __restrict__ ea,
                          const float* __restrict__ consts,
                          const int* __restrict__ off_work,
                          const int* __restrict__ blockoff,
                          float4* __restrict__ erec, float* __restrict__ part,
                          const float* __restrict__ x,
                          const unsigned short* __restrict__ wh,
                          const unsigned short* __restrict__ wl,
                          const float* __restrict__ a_s, const float* __restrict__ a_d,
                          float* __restrict__ h, float* __restrict__ alpha,
                          float* __restrict__ beta) {
    __shared__ float cs[64];
    int b = blockIdx.x, t = threadIdx.x;
    bool is_gemm = ((b & 3) == 3) && ((b >> 2) < GEMM_BLOCKS);
    if (is_gemm) {
        int tile = (b >> 2) * 4 + (t >> 6);
        if (tile < TILES_M)
            gemm_body(tile, t, x, wh, wl, a_s, a_d, h, alpha, beta);
        return;
    }
    int sid = b - min((b + 1) >> 2, GEMM_BLOCKS);
    if (t < 64) cs[t] = consts[t];
    __syncthreads();
    int e = sid * 256 + t;
    const float4* ep = (const float4*)(ea + (size_t)e * EDIM);
    float d1 = 0.f, d2 = 0.f;
#pragma unroll
    for (int i = 0; i < 8; i++) {
        float4 v = ep[i];
        d1 += v.x * cs[4 * i] + v.y * cs[4 * i + 1] + v.z * cs[4 * i + 2] + v.w * cs[4 * i + 3];
        d2 += v.x * cs[32 + 4 * i] + v.y * cs[32 + 4 * i + 1] + v.z * cs[32 + 4 * i + 2] + v.w * cs[32 + 4 * i + 3];
    }
    int d = dst[e];
    int pos = off_work[d] + blockoff[d >> 8] + rank[e];
    erec[pos] = make_float4(d1, d2, __int_as_float(src[e]), 0.f);
    float s1 = d1, s2 = d2;
    for (int off = 32; off > 0; off >>= 1) {
        s1 += __shfl_down(s1, off, 64);
        s2 += __shfl_down(s2, off, 64);
    }
    if ((t & 63) == 0) {
        int slot = (sid & 63) * 16;
        atomicAdd(&part[slot], s1);
        atomicAdd(&part[slot + 1], s2);
    }
}

// ---------------------------------------------------------------------------
// K1: agg1 on nodes [0, X_SPLIT)
__global__ void __launch_bounds__(256)
agg1_k1_kernel(const int* __restrict__ off_work, const int* __restrict__ blockoff,
               const int* __restrict__ count, const float4* __restrict__ erec,
               const float* __restrict__ h, const float* __restrict__ alpha,
               const float* __restrict__ beta, const float* __restrict__ b,
               const float* __restrict__ part, float* __restrict__ outp) {
    int i = blockIdx.x * 4 + (threadIdx.x >> 6);
    agg_body<0, 0>(i, threadIdx.x, off_work, blockoff, count, erec, h, alpha, beta,
                   b, part, nullptr, nullptr, outp);
}

// K2: agg1 on nodes [X_SPLIT, N) || gemm2 tiles [0, TILES_SPLIT), 7:1 roles.
__global__ void __launch_bounds__(256)
fused_agg_gemm_kernel(const int* __restrict__ off_work, const int* __restrict__ blockoff,
                      const int* __restrict__ count, const float4* __restrict__ erec,
                      const float* __restrict__ h1, const float* __restrict__ alpha1,
                      const float* __restrict__ beta1, const float* __restrict__ b1,
                      const float* __restrict__ part, float* __restrict__ outB,
                      const float* __restrict__ Bx,
                      const unsigned short* __restrict__ wh2,
                      const unsigned short* __restrict__ wl2,
                      const float* __restrict__ as2, const float* __restrict__ ad2,
                      float* __restrict__ C, float* __restrict__ alpha2,
                      float* __restrict__ beta2) {
    int b = blockIdx.x, t = threadIdx.x;
    bool is_gemm = ((b % 7) == 6) && ((b / 7) < GEMM_B2);
    if (is_gemm) {
        int tile = (b / 7) * 4 + (t >> 6);
        if (tile < TILES_SPLIT)
            gemm_body(tile, t, Bx, wh2, wl2, as2, ad2, C, alpha2, beta2);
        return;
    }
    int sid = b - min((b + 1) / 7, GEMM_B2);
    int i = X_SPLIT + sid * 4 + (t >> 6);
    agg_body<0, 0>(i, t, off_work, blockoff, count, erec, h1, alpha1, beta1,
                   b1, part, nullptr, nullptr, outB);
}

// K3: gemm2 remaining tiles
__global__ void __launch_bounds__(256)
gemm_k3_kernel(const float* __restrict__ Bx,
               const unsigned short* __restrict__ wh2,
               const unsigned short* __restrict__ wl2,
               const float* __restrict__ as2, const float* __restrict__ ad2,
               float* __restrict__ C, float* __restrict__ alpha2,
               float* __restrict__ beta2) {
    int tile = TILES_SPLIT + blockIdx.x * 4 + (threadIdx.x >> 6);
    if (tile >= TILES_M) return;
    gemm_body(tile, threadIdx.x, Bx, wh2, wl2, as2, ad2, C, alpha2, beta2);
}

// agg2 (FINAL): full node range
__global__ void __launch_bounds__(256)
agg2_kernel(const int* __restrict__ off_work, const int* __restrict__ blockoff,
            const int* __restrict__ count, const float4* __restrict__ erec,
            const float* __restrict__ h, const float* __restrict__ alpha,
            const float* __restrict__ beta, const float* __restrict__ b,
            const float* __restrict__ part, const float* __restrict__ Wl,
            const float* __restrict__ bl, float* __restrict__ outp) {
    int i = blockIdx.x * 4 + (threadIdx.x >> 6);
    agg_body<1, 1>(i, threadIdx.x, off_work, blockoff, count, erec, h, alpha, beta,
                   b, part, Wl, bl, outp);
}

// ---------------------------------------------------------------------------
extern "C" void kernel_launch(void* const* d_in, const int* in_sizes, int n_in,
                              void* d_out, int out_size, void* d_ws, size_t ws_size,
                              hipStream_t stream) {
    const float* x   = (const float*)d_in[0];
    const int*   src = (const int*)  d_in[1];
    const int*   dst = (const int*)  d_in[2];
    const float* ea  = (const float*)d_in[3];
    const float* W1  = (const float*)d_in[4];
    const float* We1 = (const float*)d_in[5];
    const float* as1 = (const float*)d_in[6];
    const float* ad1 = (const float*)d_in[7];
    const float* ae1 = (const float*)d_in[8];
    const float* b1  = (const float*)d_in[9];
    const float* W2  = (const float*)d_in[10];
    const float* We2 = (const float*)d_in[11];
    const float* as2 = (const float*)d_in[12];
    const float* ad2 = (const float*)d_in[13];
    const float* ae2 = (const float*)d_in[14];
    const float* b2  = (const float*)d_in[15];
    const float* Wl  = (const float*)d_in[16];
    const float* bl  = (const float*)d_in[17];
    float* out = (float*)d_out;

    float* ws      = (float*)d_ws;
    float* A       = ws;                           // [N*128] h1
    float* B       = A + (size_t)N_NODES * HIDDEN; // [N*128] conv1 out
    float* C       = B + (size_t)N_NODES * HIDDEN; // [N*128] h2
    float4* erec   = (float4*)(C + (size_t)N_NODES * HIDDEN);  // [E] packed
    unsigned short* whp1 = (unsigned short*)(erec + N_EDGES);
    unsigned short* wlp1 = whp1 + 16384;
    unsigned short* whp2 = wlp1 + 16384;
    unsigned short* wlp2 = whp2 + 16384;
    float* alpha1  = (float*)(wlp2 + 16384);       // [N]
    float* beta1   = alpha1 + N_NODES;             // [N]
    float* alpha2  = beta1 + N_NODES;              // [N]
    float* beta2   = alpha2 + N_NODES;             // [N]
    float* consts  = beta2 + N_NODES;              // [64]
    float* part    = consts + 64;                  // [64*16]
    int* count     = (int*)(part + 64 * 16);       // [N]
    int* off_work  = count + N_NODES;              // [N]
    int* blocksum  = off_work + N_NODES;           // [SCAN_BLOCKS]
    int* blockoff  = blocksum + SCAN_BLOCKS;       // [SCAN_BLOCKS]
    int* rank      = blockoff + SCAN_BLOCKS;       // [E]

    // ---- prep ----
    hipMemsetAsync(count, 0, N_NODES * sizeof(int), stream);
    hipMemsetAsync(part, 0, 64 * 16 * sizeof(float), stream);
    fused_prep_kernel<<<EB + 129, 256, 0, stream>>>(dst, count, rank,
                                                    W1, whp1, wlp1, W2, whp2, wlp2,
                                                    We1, ae1, We2, ae2, consts);
    scan1_kernel<<<SCAN_BLOCKS, 256, 0, stream>>>(count, off_work, blocksum);
    scan2_kernel<<<1, 256, 0, stream>>>(blocksum, blockoff);

    // ---- scatter + gemm1 (h1 -> A, alpha1/beta1) ----
    fused_scatter_gemm_kernel<<<EB + GEMM_BLOCKS, 256, 0, stream>>>(
        src, dst, rank, ea, consts, off_work, blockoff, erec, part,
        x, whp1, wlp1, as1, ad1, A, alpha1, beta1);

    // ---- pipelined agg1 / gemm2 ----
    agg1_k1_kernel<<<AGG_B1, 256, 0, stream>>>(off_work, blockoff, count, erec,
                                               A, alpha1, beta1, b1, part, B);
    fused_agg_gemm_kernel<<<AGG_B2 + GEMM_B2, 256, 0, stream>>>(
        off_work, blockoff, count, erec, A, alpha1, beta1, b1, part, B,
        B, whp2, wlp2, as2, ad2, C, alpha2, beta2);
    gemm_k3_kernel<<<GEMM_B3, 256, 0, stream>>>(B, whp2, wlp2, as2, ad2,
                                                C, alpha2, beta2);

    // ---- conv2 aggregate + final linear ----
    agg2_kernel<<<N_NODES / 4, 256, 0, stream>>>(off_work, blockoff, count, erec,
                                                 C, alpha2, beta2, b2, part,
                                                 Wl, bl, out);
}

// Round 16
// 209.376 us; speedup vs baseline: 2.7538x; 1.1897x over previous
//
#include <hip/hip_runtime.h>
#include <math.h>

#define N_NODES 50000
#define N_EDGES 800000
#define HIDDEN  128
#define EDIM    32
#define NEG     0.2f

typedef __attribute__((ext_vector_type(8))) short bshort8;
typedef __attribute__((ext_vector_type(4))) float f32x4;

__device__ __forceinline__ unsigned short f2bf(float f) {
    unsigned u = __builtin_bit_cast(unsigned, f);
    return (unsigned short)((u + 0x7FFFu + ((u >> 16) & 1u)) >> 16);
}
__device__ __forceinline__ float bf2f(unsigned short b) {
    unsigned u = ((unsigned)b) << 16;
    return __builtin_bit_cast(float, u);
}

#define TILES_M (N_NODES / 16)                // 3125
#define GEMM_BLOCKS ((TILES_M + 3) / 4)       // 782
#define EB (N_EDGES / 256)                    // 3125
#define SCAN_BLOCKS ((N_NODES + 255) / 256)   // 196

// pipeline split: K1 = agg1 [0,X); K2 = agg1 [X,N) || gemm2 tiles [0,X/16)
#define X_SPLIT 35008
#define TILES_SPLIT (X_SPLIT / 16)            // 2188
#define AGG_B1 (X_SPLIT / 4)                  // 8752
#define AGG_B2 ((N_NODES - X_SPLIT) / 4)      // 3748
#define GEMM_B2 ((TILES_SPLIT + 3) / 4)       // 547
#define GEMM_B3 ((TILES_M - TILES_SPLIT + 3) / 4)  // 235

// ---------------------------------------------------------------------------
__device__ __forceinline__ void pack_w_body(int idx, const float* __restrict__ W,
                                            unsigned short* __restrict__ whp,
                                            unsigned short* __restrict__ wlp) {
    int e  = idx & 7;
    int l  = (idx >> 3) & 63;
    int kc = (idx >> 9) & 3;
    int ct = (idx >> 11);
    int k   = kc * 32 + ((l >> 4) << 3) + e;
    int col = ct * 16 + (l & 15);
    float w = W[k * HIDDEN + col];
    unsigned short hb = f2bf(w);
    whp[idx] = hb;
    wlp[idx] = f2bf(w - bf2f(hb));
}

// MFMA gemm tile: h = x @ W via bf16 split; one wave per 16-row tile.
// MODE 0: write h rows + alpha/beta scalars (layer 1).
// MODE 1: NO h write; write beta + pg = {alpha, g=h_row.Wl} (layer 2).
template<int MODE>
__device__ __forceinline__ void gemm_body(int tile, int t,
                                          const float* __restrict__ x,
                                          const unsigned short* __restrict__ wh,
                                          const unsigned short* __restrict__ wl,
                                          const float* __restrict__ a_s,
                                          const float* __restrict__ a_d,
                                          const float* __restrict__ gv,
                                          float* __restrict__ h,
                                          float* __restrict__ alpha,
                                          float* __restrict__ beta,
                                          float2* __restrict__ pg) {
    int l    = t & 63;
    int row0 = tile * 16;
    int arow = l & 15;
    int kg   = l >> 4;
    bshort8 ah[4], al[4];
    const float* xr = x + (size_t)(row0 + arow) * HIDDEN + (kg << 3);
#pragma unroll
    for (int kc = 0; kc < 4; kc++) {
        float4 f0 = *(const float4*)(xr + kc * 32);
        float4 f1 = *(const float4*)(xr + kc * 32 + 4);
        float fv[8] = {f0.x, f0.y, f0.z, f0.w, f1.x, f1.y, f1.z, f1.w};
#pragma unroll
        for (int e = 0; e < 8; e++) {
            unsigned short hb = f2bf(fv[e]);
            ah[kc][e] = (short)hb;
            al[kc][e] = (short)f2bf(fv[e] - bf2f(hb));
        }
    }
    float pal[4] = {0.f, 0.f, 0.f, 0.f};
    float pbe[4] = {0.f, 0.f, 0.f, 0.f};
    float pgl[4] = {0.f, 0.f, 0.f, 0.f};
#pragma unroll
    for (int ct = 0; ct < 8; ct++) {
        f32x4 acc = {0.f, 0.f, 0.f, 0.f};
#pragma unroll
        for (int kc = 0; kc < 4; kc++) {
            int fo = (((ct * 4 + kc) * 64) + l) << 3;
            bshort8 bh = *(const bshort8*)(wh + fo);
            bshort8 bl = *(const bshort8*)(wl + fo);
            acc = __builtin_amdgcn_mfma_f32_16x16x32_bf16(ah[kc], bh, acc, 0, 0, 0);
            acc = __builtin_amdgcn_mfma_f32_16x16x32_bf16(al[kc], bh, acc, 0, 0, 0);
            acc = __builtin_amdgcn_mfma_f32_16x16x32_bf16(ah[kc], bl, acc, 0, 0, 0);
        }
        int col = ct * 16 + arow;
        float a_sc = a_s[col], a_dc = a_d[col];
        float gvc = (MODE == 1) ? gv[col] : 0.f;
#pragma unroll
        for (int j = 0; j < 4; j++) {
            if (MODE == 0)
                h[(size_t)(row0 + kg * 4 + j) * HIDDEN + col] = acc[j];
            pal[j] += acc[j] * a_sc;
            pbe[j] += acc[j] * a_dc;
            if (MODE == 1) pgl[j] += acc[j] * gvc;
        }
    }
#pragma unroll
    for (int m = 1; m < 16; m <<= 1) {
#pragma unroll
        for (int j = 0; j < 4; j++) {
            pal[j] += __shfl_xor(pal[j], m, 64);
            pbe[j] += __shfl_xor(pbe[j], m, 64);
            if (MODE == 1) pgl[j] += __shfl_xor(pgl[j], m, 64);
        }
    }
    if (arow == 0) {
#pragma unroll
        for (int j = 0; j < 4; j++) {
            int r = row0 + kg * 4 + j;
            if (MODE == 0) {
                alpha[r] = pal[j];
                beta[r]  = pbe[j];
            } else {
                beta[r] = pbe[j];
                pg[r]   = make_float2(pal[j], pgl[j]);
            }
        }
    }
}

// Gather-aggregate body (layer 1, full 128-wide output).
__device__ __forceinline__ void agg_body(int i, int t,
                                         const int* __restrict__ off_work,
                                         const int* __restrict__ blockoff,
                                         const int* __restrict__ count,
                                         const float4* __restrict__ erec,
                                         const float* __restrict__ h,
                                         const float* __restrict__ alpha,
                                         const float* __restrict__ beta,
                                         const float* __restrict__ b,
                                         const float* __restrict__ part,
                                         float* __restrict__ outp) {
    int l = t & 63;
    float ps = part[l * 16];
#pragma unroll
    for (int m = 32; m > 0; m >>= 1) ps += __shfl_xor(ps, m, 64);
    float selfc = ps * (1.f / (float)N_EDGES);
    int start = off_work[i] + blockoff[i >> 8];
    int end   = start + count[i];
    float beta_i = beta[i];
    float2 acc = make_float2(0.f, 0.f);
    float wsum = 0.f;
    for (int cb = start; cb < end; cb += 64) {
        int n = min(64, end - cb);
        int sp = 0; float wt = 0.f;
        if (l < n) {
            float4 rec = erec[cb + l];
            sp = __float_as_int(rec.z);
            float lg = alpha[sp] + beta_i + rec.x;
            lg = lg > 0.f ? lg : NEG * lg;
            wt = expf(lg);
        }
        int j = 0;
        for (; j + 8 <= n; j += 8) {
            float w8[8]; int s8[8]; float2 h8[8];
#pragma unroll
            for (int q = 0; q < 8; q++) {
                w8[q] = __shfl(wt, j + q, 64);
                s8[q] = __shfl(sp, j + q, 64);
            }
#pragma unroll
            for (int q = 0; q < 8; q++)
                h8[q] = ((const float2*)(h + (size_t)s8[q] * HIDDEN))[l];
#pragma unroll
            for (int q = 0; q < 8; q++) {
                acc.x += w8[q] * h8[q].x;
                acc.y += w8[q] * h8[q].y;
                wsum  += w8[q];
            }
        }
        for (; j + 4 <= n; j += 4) {
            float w4[4]; int s4[4]; float2 h4[4];
#pragma unroll
            for (int q = 0; q < 4; q++) {
                w4[q] = __shfl(wt, j + q, 64);
                s4[q] = __shfl(sp, j + q, 64);
            }
#pragma unroll
            for (int q = 0; q < 4; q++)
                h4[q] = ((const float2*)(h + (size_t)s4[q] * HIDDEN))[l];
#pragma unroll
            for (int q = 0; q < 4; q++) {
                acc.x += w4[q] * h4[q].x;
                acc.y += w4[q] * h4[q].y;
                wsum  += w4[q];
            }
        }
        for (; j < n; j++) {
            float w = __shfl(wt, j, 64);
            int   sj = __shfl(sp, j, 64);
            float2 hv = ((const float2*)(h + (size_t)sj * HIDDEN))[l];
            acc.x += w * hv.x;
            acc.y += w * hv.y;
            wsum  += w;
        }
    }
    float lg = alpha[i] + beta_i + selfc;
    lg = lg > 0.f ? lg : NEG * lg;
    float exi = expf(lg);
    float denom = wsum + exi + 1e-16f;
    float2 hv = ((const float2*)(h + (size_t)i * HIDDEN))[l];
    float2 bb = ((const float2*)b)[l];
    float2 v;
    v.x = (acc.x + exi * hv.x) / denom + bb.x;
    v.y = (acc.y + exi * hv.y) / denom + bb.y;
    ((float2*)(outp + (size_t)i * HIDDEN))[l] =
        make_float2(fmaxf(v.x, 0.f), fmaxf(v.y, 0.f));
}

// ---------------------------------------------------------------------------
// FUSED prep: hist (EB) | pack W1 (64) | pack W2 (64) | consts + bldot (1)
__global__ void __launch_bounds__(256)
fused_prep_kernel(const int* __restrict__ dst, int* __restrict__ count,
                  int* __restrict__ rank,
                  const float* __restrict__ W1, unsigned short* __restrict__ whp1,
                  unsigned short* __restrict__ wlp1,
                  const float* __restrict__ W2, unsigned short* __restrict__ whp2,
                  unsigned short* __restrict__ wlp2,
                  const float* __restrict__ We1, const float* __restrict__ ae1,
                  const float* __restrict__ We2, const float* __restrict__ ae2,
                  const float* __restrict__ b2, const float* __restrict__ Wlin,
                  const float* __restrict__ bl, float* __restrict__ consts) {
    int b = blockIdx.x, t = threadIdx.x;
    if (b < EB) {
        int e = b * 256 + t;
        rank[e] = atomicAdd(&count[dst[e]], 1);
    } else if (b < EB + 64) {
        pack_w_body((b - EB) * 256 + t, W1, whp1, wlp1);
    } else if (b < EB + 128) {
        pack_w_body((b - EB - 64) * 256 + t, W2, whp2, wlp2);
    } else {
        if (t < 32) {
            float acc = 0.f;
            for (int k = 0; k < HIDDEN; k++) acc += We1[t * HIDDEN + k] * ae1[k];
            consts[t] = acc;
        } else if (t < 64) {
            int j = t - 32;
            float acc = 0.f;
            for (int k = 0; k < HIDDEN; k++) acc += We2[j * HIDDEN + k] * ae2[k];
            consts[32 + j] = acc;
        } else if (t < 128) {
            // wave 1: bldot = b2.Wl + bl
            int k = t - 64;
            float p = b2[k] * Wlin[k] + b2[k + 64] * Wlin[k + 64];
            for (int off = 32; off > 0; off >>= 1) p += __shfl_down(p, off, 64);
            if (t == 64) consts[64] = p + bl[0];
        }
    }
}

// ---------------------------------------------------------------------------
// 2-phase scan (blockoff folded into consumers)
__global__ void scan1_kernel(const int* __restrict__ count,
                             int* __restrict__ off_work, int* __restrict__ blocksum) {
    __shared__ int sh[256];
    int t = threadIdx.x;
    int idx = blockIdx.x * 256 + t;
    int v = (idx < N_NODES) ? count[idx] : 0;
    sh[t] = v;
    __syncthreads();
    for (int off = 1; off < 256; off <<= 1) {
        int u = (t >= off) ? sh[t - off] : 0;
        __syncthreads();
        sh[t] += u;
        __syncthreads();
    }
    if (idx < N_NODES) off_work[idx] = sh[t] - v;
    if (t == 255) blocksum[blockIdx.x] = sh[255];
}
__global__ void scan2_kernel(int* __restrict__ blocksum, int* __restrict__ blockoff) {
    __shared__ int sh[256];
    int t = threadIdx.x;
    int v = (t < SCAN_BLOCKS) ? blocksum[t] : 0;
    sh[t] = v;
    __syncthreads();
    for (int off = 1; off < 256; off <<= 1) {
        int u = (t >= off) ? sh[t - off] : 0;
        __syncthreads();
        sh[t] += u;
        __syncthreads();
    }
    if (t < SCAN_BLOCKS) blockoff[t] = sh[t] - v;
}

// ---------------------------------------------------------------------------
// FUSED scatter_dotv + gemm1, 4:1 block-role interleave.
__global__ void __launch_bounds__(256)
fused_scatter_gemm_kernel(const int* __restrict__ src, const int* __restrict__ dst,
                          const int* __restrict__ rank,
                          const float* __restrict__ ea,
                          const float* __restrict__ consts,
                          const int* __restrict__ off_work,
                          const int* __restrict__ blockoff,
                          float4* __restrict__ erec, float* __restrict__ part,
                          const float* __restrict__ x,
                          const unsigned short* __restrict__ wh,
                          const unsigned short* __restrict__ wl,
                          const float* __restrict__ a_s, const float* __restrict__ a_d,
                          float* __restrict__ h, float* __restrict__ alpha,
                          float* __restrict__ beta) {
    __shared__ float cs[64];
    int b = blockIdx.x, t = threadIdx.x;
    bool is_gemm = ((b & 3) == 3) && ((b >> 2) < GEMM_BLOCKS);
    if (is_gemm) {
        int tile = (b >> 2) * 4 + (t >> 6);
        if (tile < TILES_M)
            gemm_body<0>(tile, t, x, wh, wl, a_s, a_d, nullptr, h, alpha, beta, nullptr);
        return;
    }
    int sid = b - min((b + 1) >> 2, GEMM_BLOCKS);
    if (t < 64) cs[t] = consts[t];
    __syncthreads();
    int e = sid * 256 + t;
    const float4* ep = (const float4*)(ea + (size_t)e * EDIM);
    float d1 = 0.f, d2 = 0.f;
#pragma unroll
    for (int i = 0; i < 8; i++) {
        float4 v = ep[i];
        d1 += v.x * cs[4 * i] + v.y * cs[4 * i + 1] + v.z * cs[4 * i + 2] + v.w * cs[4 * i + 3];
        d2 += v.x * cs[32 + 4 * i] + v.y * cs[32 + 4 * i + 1] + v.z * cs[32 + 4 * i + 2] + v.w * cs[32 + 4 * i + 3];
    }
    int d = dst[e];
    int pos = off_work[d] + blockoff[d >> 8] + rank[e];
    erec[pos] = make_float4(d1, d2, __int_as_float(src[e]), 0.f);
    float s1 = d1, s2 = d2;
    for (int off = 32; off > 0; off >>= 1) {
        s1 += __shfl_down(s1, off, 64);
        s2 += __shfl_down(s2, off, 64);
    }
    if ((t & 63) == 0) {
        int slot = (sid & 63) * 16;
        atomicAdd(&part[slot], s1);
        atomicAdd(&part[slot + 1], s2);
    }
}

// ---------------------------------------------------------------------------
// K1: agg1 on nodes [0, X_SPLIT)
__global__ void __launch_bounds__(256)
agg1_k1_kernel(const int* __restrict__ off_work, const int* __restrict__ blockoff,
               const int* __restrict__ count, const float4* __restrict__ erec,
               const float* __restrict__ h, const float* __restrict__ alpha,
               const float* __restrict__ beta, const float* __restrict__ b,
               const float* __restrict__ part, float* __restrict__ outp) {
    int i = blockIdx.x * 4 + (threadIdx.x >> 6);
    agg_body(i, threadIdx.x, off_work, blockoff, count, erec, h, alpha, beta,
             b, part, outp);
}

// K2: agg1 on nodes [X_SPLIT, N) || gemm2 tiles [0, TILES_SPLIT), 7:1 roles.
__global__ void __launch_bounds__(256)
fused_agg_gemm_kernel(const int* __restrict__ off_work, const int* __restrict__ blockoff,
                      const int* __restrict__ count, const float4* __restrict__ erec,
                      const float* __restrict__ h1, const float* __restrict__ alpha1,
                      const float* __restrict__ beta1, const float* __restrict__ b1,
                      const float* __restrict__ part, float* __restrict__ outB,
                      const float* __restrict__ Bx,
                      const unsigned short* __restrict__ wh2,
                      const unsigned short* __restrict__ wl2,
                      const float* __restrict__ as2, const float* __restrict__ ad2,
                      const float* __restrict__ Wlin,
                      float* __restrict__ beta2, float2* __restrict__ pg) {
    int b = blockIdx.x, t = threadIdx.x;
    bool is_gemm = ((b % 7) == 6) && ((b / 7) < GEMM_B2);
    if (is_gemm) {
        int tile = (b / 7) * 4 + (t >> 6);
        if (tile < TILES_SPLIT)
            gemm_body<1>(tile, t, Bx, wh2, wl2, as2, ad2, Wlin,
                         nullptr, nullptr, beta2, pg);
        return;
    }
    int sid = b - min((b + 1) / 7, GEMM_B2);
    int i = X_SPLIT + sid * 4 + (t >> 6);
    agg_body(i, t, off_work, blockoff, count, erec, h1, alpha1, beta1,
             b1, part, outB);
}

// K3: gemm2 remaining tiles
__global__ void __launch_bounds__(256)
gemm_k3_kernel(const float* __restrict__ Bx,
               const unsigned short* __restrict__ wh2,
               const unsigned short* __restrict__ wl2,
               const float* __restrict__ as2, const float* __restrict__ ad2,
               const float* __restrict__ Wlin,
               float* __restrict__ beta2, float2* __restrict__ pg) {
    int tile = TILES_SPLIT + blockIdx.x * 4 + (threadIdx.x >> 6);
    if (tile >= TILES_M) return;
    gemm_body<1>(tile, threadIdx.x, Bx, wh2, wl2, as2, ad2, Wlin,
                 nullptr, nullptr, beta2, pg);
}

// ---------------------------------------------------------------------------
// agg2-lite: out[i] = relu((Σ w·g[src] + exi·g[i])/denom + bldot)
// Scalar gathers from the 400 KB pg table (L2-resident). Lane-parallel edges.
__global__ void __launch_bounds__(256)
agg2_lite_kernel(const int* __restrict__ off_work, const int* __restrict__ blockoff,
                 const int* __restrict__ count, const float4* __restrict__ erec,
                 const float2* __restrict__ pg, const float* __restrict__ beta2,
                 const float* __restrict__ part, const float* __restrict__ consts,
                 float* __restrict__ out) {
    int t = threadIdx.x, l = t & 63;
    int i = blockIdx.x * 4 + (t >> 6);
    float ps = part[l * 16 + 1];
#pragma unroll
    for (int m = 32; m > 0; m >>= 1) ps += __shfl_xor(ps, m, 64);
    float selfc = ps * (1.f / (float)N_EDGES);
    int start = off_work[i] + blockoff[i >> 8];
    int end   = start + count[i];
    float beta_i = beta2[i];
    float wsum = 0.f, gsum = 0.f;
    for (int e = start + l; e < end; e += 64) {
        float4 rec = erec[e];
        int sp = __float_as_int(rec.z);
        float2 ag = pg[sp];
        float lg = ag.x + beta_i + rec.y;
        lg = lg > 0.f ? lg : NEG * lg;
        float w = expf(lg);
        wsum += w;
        gsum += w * ag.y;
    }
    for (int m = 32; m > 0; m >>= 1) {
        wsum += __shfl_xor(wsum, m, 64);
        gsum += __shfl_xor(gsum, m, 64);
    }
    if (l == 0) {
        float2 agi = pg[i];
        float lg = agi.x + beta_i + selfc;
        lg = lg > 0.f ? lg : NEG * lg;
        float exi = expf(lg);
        float denom = wsum + exi + 1e-16f;
        out[i] = fmaxf((gsum + exi * agi.y) / denom + consts[64], 0.f);
    }
}

// ---------------------------------------------------------------------------
extern "C" void kernel_launch(void* const* d_in, const int* in_sizes, int n_in,
                              void* d_out, int out_size, void* d_ws, size_t ws_size,
                              hipStream_t stream) {
    const float* x   = (const float*)d_in[0];
    const int*   src = (const int*)  d_in[1];
    const int*   dst = (const int*)  d_in[2];
    const float* ea  = (const float*)d_in[3];
    const float* W1  = (const float*)d_in[4];
    const float* We1 = (const float*)d_in[5];
    const float* as1 = (const float*)d_in[6];
    const float* ad1 = (const float*)d_in[7];
    const float* ae1 = (const float*)d_in[8];
    const float* b1  = (const float*)d_in[9];
    const float* W2  = (const float*)d_in[10];
    const float* We2 = (const float*)d_in[11];
    const float* as2 = (const float*)d_in[12];
    const float* ad2 = (const float*)d_in[13];
    const float* ae2 = (const float*)d_in[14];
    const float* b2  = (const float*)d_in[15];
    const float* Wl  = (const float*)d_in[16];
    const float* bl  = (const float*)d_in[17];
    float* out = (float*)d_out;

    float* ws      = (float*)d_ws;
    float* A       = ws;                           // [N*128] h1
    float* B       = A + (size_t)N_NODES * HIDDEN; // [N*128] conv1 out
    float4* erec   = (float4*)(B + (size_t)N_NODES * HIDDEN);  // [E] packed
    unsigned short* whp1 = (unsigned short*)(erec + N_EDGES);
    unsigned short* wlp1 = whp1 + 16384;
    unsigned short* whp2 = wlp1 + 16384;
    unsigned short* wlp2 = whp2 + 16384;
    float* alpha1  = (float*)(wlp2 + 16384);       // [N]
    float* beta1   = alpha1 + N_NODES;             // [N]
    float* beta2   = beta1 + N_NODES;              // [N]
    float2* pg     = (float2*)(beta2 + N_NODES);   // [N] {alpha2, g}
    float* consts  = (float*)(pg + N_NODES);       // [80]
    float* part    = consts + 80;                  // [64*16]
    int* count     = (int*)(part + 64 * 16);       // [N]
    int* off_work  = count + N_NODES;              // [N]
    int* blocksum  = off_work + N_NODES;           // [SCAN_BLOCKS]
    int* blockoff  = blocksum + SCAN_BLOCKS;       // [SCAN_BLOCKS]
    int* rank      = blockoff + SCAN_BLOCKS;       // [E]

    // ---- prep ----
    hipMemsetAsync(count, 0, N_NODES * sizeof(int), stream);
    hipMemsetAsync(part, 0, 64 * 16 * sizeof(float), stream);
    fused_prep_kernel<<<EB + 129, 256, 0, stream>>>(dst, count, rank,
                                                    W1, whp1, wlp1, W2, whp2, wlp2,
                                                    We1, ae1, We2, ae2,
                                                    b2, Wl, bl, consts);
    scan1_kernel<<<SCAN_BLOCKS, 256, 0, stream>>>(count, off_work, blocksum);
    scan2_kernel<<<1, 256, 0, stream>>>(blocksum, blockoff);

    // ---- scatter + gemm1 (h1 -> A, alpha1/beta1) ----
    fused_scatter_gemm_kernel<<<EB + GEMM_BLOCKS, 256, 0, stream>>>(
        src, dst, rank, ea, consts, off_work, blockoff, erec, part,
        x, whp1, wlp1, as1, ad1, A, alpha1, beta1);

    // ---- pipelined agg1 / gemm2 ----
    agg1_k1_kernel<<<AGG_B1, 256, 0, stream>>>(off_work, blockoff, count, erec,
                                               A, alpha1, beta1, b1, part, B);
    fused_agg_gemm_kernel<<<AGG_B2 + GEMM_B2, 256, 0, stream>>>(
        off_work, blockoff, count, erec, A, alpha1, beta1, b1, part, B,
        B, whp2, wlp2, as2, ad2, Wl, beta2, pg);
    gemm_k3_kernel<<<GEMM_B3, 256, 0, stream>>>(B, whp2, wlp2, as2, ad2,
                                                Wl, beta2, pg);

    // ---- conv2 aggregate + final linear (scalar form) ----
    agg2_lite_kernel<<<N_NODES / 4, 256, 0, stream>>>(off_work, blockoff, count,
                                                      erec, pg, beta2, part,
                                                      consts, out);
}